// Round 1
// baseline (806.270 us; speedup 1.0000x reference)
//
#include <hip/hip_runtime.h>
#include <stdint.h>

#define B_ 8
#define N_ 1374
#define C_ 768
#define H_ 12
#define HD_ 64
#define HID_ 3072
#define M_ (B_*N_)        // 10992
#define MPAD_ 11008       // 86 * 128
#define QT_ 22            // ceil(N/64)

typedef __attribute__((ext_vector_type(8))) short short8;
typedef __attribute__((ext_vector_type(4))) float f32x4;

__device__ __forceinline__ unsigned short f2bf(float f) {
  unsigned u = __float_as_uint(f);
  u += 0x7FFF + ((u >> 16) & 1);
  return (unsigned short)(u >> 16);
}
__device__ __forceinline__ float bf2f(unsigned short h) {
  return __uint_as_float(((unsigned)h) << 16);
}

#if __has_builtin(__builtin_amdgcn_global_load_lds)
#define HAVE_GLL 1
#endif

__device__ __forceinline__ void gld16(const unsigned short* g, unsigned short* l) {
#ifdef HAVE_GLL
  __builtin_amdgcn_global_load_lds((const __attribute__((address_space(1))) void*)g,
                                   (__attribute__((address_space(3))) void*)l, 16, 0, 0);
#else
  *(short8*)l = *(const short8*)g;
#endif
}

// ---------------- f32 -> bf16 conversion (weights) ----------------
__global__ __launch_bounds__(256) void cvt_kernel(const float* __restrict__ in,
                                                  unsigned short* __restrict__ out, int n4) {
  int id = blockIdx.x * 256 + threadIdx.x;
  if (id >= n4) return;
  float4 v = ((const float4*)in)[id];
  ushort4 o;
  o.x = f2bf(v.x); o.y = f2bf(v.y); o.z = f2bf(v.z); o.w = f2bf(v.w);
  ((ushort4*)out)[id] = o;
}

// ---------------- LayerNorm (f32 in, bf16 out) ----------------
__global__ __launch_bounds__(256) void ln_kernel(const float* __restrict__ in,
    const float* __restrict__ g, const float* __restrict__ bta,
    unsigned short* __restrict__ out) {
  int row = blockIdx.x;
  int t = threadIdx.x;
  const float* xr = in + (size_t)row * C_;
  float v0 = xr[t], v1 = xr[t + 256], v2 = xr[t + 512];
  float s1 = v0 + v1 + v2;
  float s2 = v0*v0 + v1*v1 + v2*v2;
  for (int off = 1; off < 64; off <<= 1) {
    s1 += __shfl_xor(s1, off, 64);
    s2 += __shfl_xor(s2, off, 64);
  }
  __shared__ float r1[4], r2[4];
  int wave = t >> 6, lane = t & 63;
  if (lane == 0) { r1[wave] = s1; r2[wave] = s2; }
  __syncthreads();
  float tot1 = r1[0] + r1[1] + r1[2] + r1[3];
  float tot2 = r2[0] + r2[1] + r2[2] + r2[3];
  float mu = tot1 * (1.0f / C_);
  float var = tot2 * (1.0f / C_) - mu * mu;
  float rs = rsqrtf(var + 1e-5f);
  size_t ob = (size_t)row * C_;
  out[ob + t]       = f2bf((v0 - mu) * rs * g[t]       + bta[t]);
  out[ob + t + 256] = f2bf((v1 - mu) * rs * g[t + 256] + bta[t + 256]);
  out[ob + t + 512] = f2bf((v2 - mu) * rs * g[t + 512] + bta[t + 512]);
}

// ---------------- GEMM: out[M,N] = A[M,K](bf16) * W[N,K]^T(bf16) + epilogue ----------------
// EPI 0: bf16 out + bias0           (qkv)
// EPI 1: f32 out = resid + v + bias (proj + residual), row-guarded
// EPI 2: bf16 out + split bias b1/b2 at col 3072 (w1|w2 fused)
// EPI 3: f32 out += v + bias        (w3 + residual already in out), row-guarded
template<int EPI>
__global__ __launch_bounds__(256, 2) void gemm_bt(
    const unsigned short* __restrict__ A,
    const unsigned short* __restrict__ W,
    void* __restrict__ outp,
    const float* __restrict__ bias0,
    const float* __restrict__ bias1,
    const float* __restrict__ resid,
    int K, int ldo, int Mvalid)
{
  __shared__ __align__(16) unsigned short As[4096];
  __shared__ __align__(16) unsigned short Bs[4096];
  const int t = threadIdx.x;
  const int lane = t & 63;
  const int wave = t >> 6;
  const int wm = (wave >> 1) * 64;
  const int wn = (wave & 1) * 64;
  const int lr = lane & 15;
  const int lk = (lane >> 4) * 8;
  const int tm0 = blockIdx.y * 128;
  const int tn0 = blockIdx.x * 128;
  const int r0 = t >> 2;
  const int c0 = (t & 3) * 8;
  const unsigned short* ga0 = A + (size_t)(tm0 + r0) * K + c0;
  const unsigned short* ga1 = A + (size_t)(tm0 + 64 + r0) * K + c0;
  const unsigned short* gb0 = W + (size_t)(tn0 + r0) * K + c0;
  const unsigned short* gb1 = W + (size_t)(tn0 + 64 + r0) * K + c0;
  f32x4 zero = {0.f, 0.f, 0.f, 0.f};
  f32x4 acc[4][4];
#pragma unroll
  for (int mi = 0; mi < 4; ++mi)
#pragma unroll
    for (int ni = 0; ni < 4; ++ni) acc[mi][ni] = zero;

  for (int kt = 0; kt < K; kt += 32) {
    __syncthreads();
    gld16(ga0 + kt, &As[t * 8]);
    gld16(ga1 + kt, &As[2048 + t * 8]);
    gld16(gb0 + kt, &Bs[t * 8]);
    gld16(gb1 + kt, &Bs[2048 + t * 8]);
    __syncthreads();
    short8 af[4], bfr[4];
#pragma unroll
    for (int mi = 0; mi < 4; ++mi) af[mi] = *(const short8*)&As[(wm + mi * 16 + lr) * 32 + lk];
#pragma unroll
    for (int ni = 0; ni < 4; ++ni) bfr[ni] = *(const short8*)&Bs[(wn + ni * 16 + lr) * 32 + lk];
#pragma unroll
    for (int mi = 0; mi < 4; ++mi)
#pragma unroll
      for (int ni = 0; ni < 4; ++ni)
        acc[mi][ni] = __builtin_amdgcn_mfma_f32_16x16x32_bf16(af[mi], bfr[ni], acc[mi][ni], 0, 0, 0);
  }
#pragma unroll
  for (int mi = 0; mi < 4; ++mi) {
#pragma unroll
    for (int ni = 0; ni < 4; ++ni) {
      int col = tn0 + wn + ni * 16 + lr;
      float bval;
      if (EPI == 2) bval = (col < 3072) ? bias0[col] : bias1[col - 3072];
      else bval = bias0[col];
#pragma unroll
      for (int r = 0; r < 4; ++r) {
        int row = tm0 + wm + mi * 16 + (lane >> 4) * 4 + r;
        float v = acc[mi][ni][r] + bval;
        size_t idx = (size_t)row * ldo + col;
        if (EPI == 0 || EPI == 2) {
          ((unsigned short*)outp)[idx] = f2bf(v);
        } else if (EPI == 1) {
          if (row < Mvalid) ((float*)outp)[idx] = resid[idx] + v;
        } else {
          if (row < Mvalid) ((float*)outp)[idx] = ((float*)outp)[idx] + v;
        }
      }
    }
  }
}

// ---------------- RoPE in-place on qkv (bf16), q and k parts ----------------
__global__ __launch_bounds__(256) void rope_kernel(unsigned short* __restrict__ qkv,
                                                   const float* __restrict__ freqs) {
  int id = blockIdx.x * 256 + threadIdx.x;   // < M_*H_*32
  int e = id & 31;
  int hm = id >> 5;
  int head = hm % H_;
  int m = hm / H_;
  int n = m % N_;
  float f1 = freqs[n * HD_ + e];
  float f2 = freqs[n * HD_ + e + 32];
  float c1 = cosf(f1), s1 = sinf(f1);
  float c2 = cosf(f2), s2 = sinf(f2);
  unsigned short* base = qkv + (size_t)m * 2304 + head * HD_ + e;
#pragma unroll
  for (int part = 0; part < 2; ++part) {
    unsigned short* p = base + part * 768;
    float x1 = bf2f(p[0]);
    float x2 = bf2f(p[32]);
    p[0]  = f2bf(x1 * c1 - x2 * s1);
    p[32] = f2bf(x2 * c2 + x1 * s2);
  }
}

// ---------------- Attention: MFMA flash-style, no max-subtract ----------------
// block = 256 thr (4 waves), handles (b, head, 64 q rows); wave owns 16 q rows.
__global__ __launch_bounds__(256, 2) void attn_kernel(
    const unsigned short* __restrict__ qkv,   // [MPAD_,2304] roped
    unsigned short* __restrict__ o2)          // [MPAD_,768]
{
  __shared__ __align__(16) unsigned short Vt[64 * 72];      // V^T: [d][j], stride 72
  __shared__ __align__(16) unsigned short Ps[4 * 16 * 72];  // per-wave P: [m][j], stride 72
  int bidx = blockIdx.x;
  int qt = bidx % QT_;
  int bh = bidx / QT_;
  int head = bh % H_;
  int b = bh / H_;
  int t = threadIdx.x, lane = t & 63, wave = t >> 6;
  int lr = lane & 15, lg = lane >> 4;

  int i = qt * 64 + wave * 16 + lr;
  int iq = (i < N_) ? i : (N_ - 1);
  const unsigned short* qrow = qkv + (size_t)(b * N_ + iq) * 2304 + head * HD_;
  short8 aq0 = *(const short8*)(qrow + lg * 8);
  short8 aq1 = *(const short8*)(qrow + 32 + lg * 8);

  f32x4 zero = {0.f, 0.f, 0.f, 0.f};
  f32x4 acc[4];
#pragma unroll
  for (int dt = 0; dt < 4; ++dt) acc[dt] = zero;
  float den[4] = {0.f, 0.f, 0.f, 0.f};

  int vj = t >> 3;           // 0..31
  int vc = (t & 7) * 8;      // 0..56

  for (int jt = 0; jt < QT_; ++jt) {
    __syncthreads();
    // stage V^T
#pragma unroll
    for (int p = 0; p < 2; ++p) {
      int j = vj + p * 32;
      int jg = jt * 64 + j;
      int jc = (jg < N_) ? jg : (N_ - 1);
      const unsigned short* vrow = qkv + (size_t)(b * N_ + jc) * 2304 + 1536 + head * HD_ + vc;
      ushort4 va = *(const ushort4*)vrow;
      ushort4 vb = *(const ushort4*)(vrow + 4);
      Vt[(vc + 0) * 72 + j] = va.x; Vt[(vc + 1) * 72 + j] = va.y;
      Vt[(vc + 2) * 72 + j] = va.z; Vt[(vc + 3) * 72 + j] = va.w;
      Vt[(vc + 4) * 72 + j] = vb.x; Vt[(vc + 5) * 72 + j] = vb.y;
      Vt[(vc + 6) * 72 + j] = vb.z; Vt[(vc + 7) * 72 + j] = vb.w;
    }
    __syncthreads();
    // S = Q K^T per wave, exp, write P to LDS
#pragma unroll
    for (int st = 0; st < 4; ++st) {
      int j = jt * 64 + st * 16 + lr;
      int jc = (j < N_) ? j : (N_ - 1);
      const unsigned short* krow = qkv + (size_t)(b * N_ + jc) * 2304 + 768 + head * HD_;
      short8 kb0 = *(const short8*)(krow + lg * 8);
      short8 kb1 = *(const short8*)(krow + 32 + lg * 8);
      f32x4 s = zero;
      s = __builtin_amdgcn_mfma_f32_16x16x32_bf16(aq0, kb0, s, 0, 0, 0);
      s = __builtin_amdgcn_mfma_f32_16x16x32_bf16(aq1, kb1, s, 0, 0, 0);
      bool valid = (j < N_);
#pragma unroll
      for (int r = 0; r < 4; ++r) {
        float pv = valid ? __expf(s[r] * 0.125f) : 0.f;
        den[r] += pv;
        Ps[wave * 1152 + (lg * 4 + r) * 72 + st * 16 + lr] = f2bf(pv);
      }
    }
    // PV: A = P (LDS round-trip to A-layout), B = V^T
    short8 pa0 = *(const short8*)&Ps[wave * 1152 + lr * 72 + lg * 8];
    short8 pa1 = *(const short8*)&Ps[wave * 1152 + lr * 72 + 32 + lg * 8];
#pragma unroll
    for (int dt = 0; dt < 4; ++dt) {
      short8 bv0 = *(const short8*)&Vt[(dt * 16 + lr) * 72 + lg * 8];
      short8 bv1 = *(const short8*)&Vt[(dt * 16 + lr) * 72 + 32 + lg * 8];
      acc[dt] = __builtin_amdgcn_mfma_f32_16x16x32_bf16(pa0, bv0, acc[dt], 0, 0, 0);
      acc[dt] = __builtin_amdgcn_mfma_f32_16x16x32_bf16(pa1, bv1, acc[dt], 0, 0, 0);
    }
  }
  // reduce den across the 16 lanes of each quad-group
#pragma unroll
  for (int r = 0; r < 4; ++r) {
    float d = den[r];
    d += __shfl_xor(d, 1, 64);
    d += __shfl_xor(d, 2, 64);
    d += __shfl_xor(d, 4, 64);
    d += __shfl_xor(d, 8, 64);
    den[r] = d;
  }
#pragma unroll
  for (int dt = 0; dt < 4; ++dt)
#pragma unroll
    for (int r = 0; r < 4; ++r) {
      int irow = qt * 64 + wave * 16 + lg * 4 + r;
      if (irow < N_)
        o2[(size_t)(b * N_ + irow) * C_ + head * HD_ + dt * 16 + lr] = f2bf(acc[dt][r] / den[r]);
    }
}

// ---------------- SwiGLU: hid = silu(a1) * a2 ----------------
__global__ __launch_bounds__(256) void swiglu_kernel(const unsigned short* __restrict__ a12,
                                                     unsigned short* __restrict__ hid) {
  int id = blockIdx.x * 256 + threadIdx.x;   // < MPAD_*768
  int m = id / 768;
  int gj = id - m * 768;
  int j = gj * 4;
  const unsigned short* p1 = a12 + (size_t)m * 6144 + j;
  const unsigned short* p2 = p1 + 3072;
  ushort4 u1 = *(const ushort4*)p1;
  ushort4 u2 = *(const ushort4*)p2;
  float a0 = bf2f(u1.x), a1 = bf2f(u1.y), a2 = bf2f(u1.z), a3 = bf2f(u1.w);
  float b0 = bf2f(u2.x), b1 = bf2f(u2.y), b2 = bf2f(u2.z), b3 = bf2f(u2.w);
  ushort4 o;
  o.x = f2bf(a0 / (1.f + __expf(-a0)) * b0);
  o.y = f2bf(a1 / (1.f + __expf(-a1)) * b1);
  o.z = f2bf(a2 / (1.f + __expf(-a2)) * b2);
  o.w = f2bf(a3 / (1.f + __expf(-a3)) * b3);
  *(ushort4*)(hid + (size_t)m * 3072 + j) = o;
}

extern "C" void kernel_launch(void* const* d_in, const int* in_sizes, int n_in,
                              void* d_out, int out_size, void* d_ws, size_t ws_size,
                              hipStream_t stream) {
  const float* x      = (const float*)d_in[0];
  const float* freqs  = (const float*)d_in[1];
  const float* ln1_g  = (const float*)d_in[2];
  const float* ln1_b  = (const float*)d_in[3];
  const float* qkv_w  = (const float*)d_in[4];
  const float* qkv_b  = (const float*)d_in[5];
  const float* proj_w = (const float*)d_in[6];
  const float* proj_b = (const float*)d_in[7];
  const float* ln2_g  = (const float*)d_in[8];
  const float* ln2_b  = (const float*)d_in[9];
  const float* w1     = (const float*)d_in[10];
  const float* b1     = (const float*)d_in[11];
  const float* w2     = (const float*)d_in[12];
  const float* b2     = (const float*)d_in[13];
  const float* w3     = (const float*)d_in[14];
  const float* b3     = (const float*)d_in[15];
  float* out = (float*)d_out;
  char* ws = (char*)d_ws;

  // workspace layout (bytes)
  unsigned short* hB     = (unsigned short*)(ws + 0);          // [MPAD,768] bf16  16,908,288
  unsigned short* wqkvB  = (unsigned short*)(ws + 16908288);   // [2304,768]        3,538,944
  unsigned short* wprojB = (unsigned short*)(ws + 20447232);   // [768,768]         1,179,648
  unsigned short* w12B   = (unsigned short*)(ws + 21626880);   // [6144,768]        9,437,184
  unsigned short* w3B    = (unsigned short*)(ws + 31064064);   // [768,3072]        4,718,592
  unsigned short* qkvB   = (unsigned short*)(ws + 35782656);   // [MPAD,2304]      50,724,864
  unsigned short* o2B    = (unsigned short*)(ws + 86507520);   // [MPAD,768]       16,908,288
  unsigned short* a12B   = (unsigned short*)(ws + 103415808);  // [MPAD,6144]     135,266,304
  unsigned short* hidB   = qkvB;  // [MPAD,3072] overlaps dead qkv+o2 (67,633,152 fits exactly)

  // weights -> bf16
  cvt_kernel<<<1728, 256, 0, stream>>>(qkv_w, wqkvB, 2304 * 768 / 4);
  cvt_kernel<<<576,  256, 0, stream>>>(proj_w, wprojB, 768 * 768 / 4);
  cvt_kernel<<<2304, 256, 0, stream>>>(w1, w12B, 3072 * 768 / 4);
  cvt_kernel<<<2304, 256, 0, stream>>>(w2, w12B + 3072 * 768, 3072 * 768 / 4);
  cvt_kernel<<<2304, 256, 0, stream>>>(w3, w3B, 768 * 3072 / 4);

  // attention branch
  ln_kernel<<<M_, 256, 0, stream>>>(x, ln1_g, ln1_b, hB);
  gemm_bt<0><<<dim3(18, 86), 256, 0, stream>>>(hB, wqkvB, qkvB, qkv_b, nullptr, nullptr, 768, 2304, M_);
  rope_kernel<<<16488, 256, 0, stream>>>(qkvB, freqs);
  attn_kernel<<<B_ * H_ * QT_, 256, 0, stream>>>(qkvB, o2B);
  gemm_bt<1><<<dim3(6, 86), 256, 0, stream>>>(o2B, wprojB, out, proj_b, nullptr, x, 768, 768, M_);

  // MLP branch
  ln_kernel<<<M_, 256, 0, stream>>>(out, ln2_g, ln2_b, hB);
  gemm_bt<2><<<dim3(48, 86), 256, 0, stream>>>(hB, w12B, a12B, b1, b2, nullptr, 768, 6144, M_);
  swiglu_kernel<<<33024, 256, 0, stream>>>(a12B, hidB);
  gemm_bt<3><<<dim3(6, 86), 256, 0, stream>>>(hidB, w3B, out, b3, nullptr, nullptr, 3072, 768, M_);
}

// Round 2
// 696.010 us; speedup vs baseline: 1.1584x; 1.1584x over previous
//
#include <hip/hip_runtime.h>
#include <stdint.h>

#define B_ 8
#define N_ 1374
#define C_ 768
#define H_ 12
#define HD_ 64
#define HID_ 3072
#define M_ (B_*N_)        // 10992
#define MPAD_ 11008       // 86 * 128
#define QT_ 22            // ceil(N/64)  (j tiles)
#define QT2_ 11           // ceil(N/128) (q tiles)

typedef __attribute__((ext_vector_type(8))) short short8;
typedef __attribute__((ext_vector_type(4))) float f32x4;
typedef __attribute__((ext_vector_type(4))) _Float16 half4;

__device__ __forceinline__ unsigned short f2bf(float f) {
  unsigned u = __float_as_uint(f);
  u += 0x7FFF + ((u >> 16) & 1);
  return (unsigned short)(u >> 16);
}
__device__ __forceinline__ float bf2f(unsigned short h) {
  return __uint_as_float(((unsigned)h) << 16);
}

#if __has_builtin(__builtin_amdgcn_global_load_lds)
#define HAVE_GLL 1
#endif

__device__ __forceinline__ void gld16(const unsigned short* g, unsigned short* l) {
#ifdef HAVE_GLL
  __builtin_amdgcn_global_load_lds((const __attribute__((address_space(1))) void*)g,
                                   (__attribute__((address_space(3))) void*)l, 16, 0, 0);
#else
  *(short8*)l = *(const short8*)g;
#endif
}

// ---------------- f32 -> bf16 conversion (weights) ----------------
__global__ __launch_bounds__(256) void cvt_kernel(const float* __restrict__ in,
                                                  unsigned short* __restrict__ out, int n4) {
  int id = blockIdx.x * 256 + threadIdx.x;
  if (id >= n4) return;
  float4 v = ((const float4*)in)[id];
  ushort4 o;
  o.x = f2bf(v.x); o.y = f2bf(v.y); o.z = f2bf(v.z); o.w = f2bf(v.w);
  ((ushort4*)out)[id] = o;
}

// ---------------- LayerNorm (f32 in, bf16 out) ----------------
__global__ __launch_bounds__(256) void ln_kernel(const float* __restrict__ in,
    const float* __restrict__ g, const float* __restrict__ bta,
    unsigned short* __restrict__ out) {
  int row = blockIdx.x;
  int t = threadIdx.x;
  const float* xr = in + (size_t)row * C_;
  float v0 = xr[t], v1 = xr[t + 256], v2 = xr[t + 512];
  float s1 = v0 + v1 + v2;
  float s2 = v0*v0 + v1*v1 + v2*v2;
  for (int off = 1; off < 64; off <<= 1) {
    s1 += __shfl_xor(s1, off, 64);
    s2 += __shfl_xor(s2, off, 64);
  }
  __shared__ float r1[4], r2[4];
  int wave = t >> 6, lane = t & 63;
  if (lane == 0) { r1[wave] = s1; r2[wave] = s2; }
  __syncthreads();
  float tot1 = r1[0] + r1[1] + r1[2] + r1[3];
  float tot2 = r2[0] + r2[1] + r2[2] + r2[3];
  float mu = tot1 * (1.0f / C_);
  float var = tot2 * (1.0f / C_) - mu * mu;
  float rs = rsqrtf(var + 1e-5f);
  size_t ob = (size_t)row * C_;
  out[ob + t]       = f2bf((v0 - mu) * rs * g[t]       + bta[t]);
  out[ob + t + 256] = f2bf((v1 - mu) * rs * g[t + 256] + bta[t + 256]);
  out[ob + t + 512] = f2bf((v2 - mu) * rs * g[t + 512] + bta[t + 512]);
}

// ---------------- GEMM: out[M,N] = A[M,K](bf16) * W[N,K]^T(bf16) + epilogue ----------------
template<int EPI>
__global__ __launch_bounds__(256, 2) void gemm_bt(
    const unsigned short* __restrict__ A,
    const unsigned short* __restrict__ W,
    void* __restrict__ outp,
    const float* __restrict__ bias0,
    const float* __restrict__ bias1,
    const float* __restrict__ resid,
    int K, int ldo, int Mvalid)
{
  __shared__ __align__(16) unsigned short As[4096];
  __shared__ __align__(16) unsigned short Bs[4096];
  const int t = threadIdx.x;
  const int lane = t & 63;
  const int wave = t >> 6;
  const int wm = (wave >> 1) * 64;
  const int wn = (wave & 1) * 64;
  const int lr = lane & 15;
  const int lk = (lane >> 4) * 8;
  const int tm0 = blockIdx.y * 128;
  const int tn0 = blockIdx.x * 128;
  const int r0 = t >> 2;
  const int c0 = (t & 3) * 8;
  const unsigned short* ga0 = A + (size_t)(tm0 + r0) * K + c0;
  const unsigned short* ga1 = A + (size_t)(tm0 + 64 + r0) * K + c0;
  const unsigned short* gb0 = W + (size_t)(tn0 + r0) * K + c0;
  const unsigned short* gb1 = W + (size_t)(tn0 + 64 + r0) * K + c0;
  f32x4 zero = {0.f, 0.f, 0.f, 0.f};
  f32x4 acc[4][4];
#pragma unroll
  for (int mi = 0; mi < 4; ++mi)
#pragma unroll
    for (int ni = 0; ni < 4; ++ni) acc[mi][ni] = zero;

  for (int kt = 0; kt < K; kt += 32) {
    __syncthreads();
    gld16(ga0 + kt, &As[t * 8]);
    gld16(ga1 + kt, &As[2048 + t * 8]);
    gld16(gb0 + kt, &Bs[t * 8]);
    gld16(gb1 + kt, &Bs[2048 + t * 8]);
    __syncthreads();
    short8 af[4], bfr[4];
#pragma unroll
    for (int mi = 0; mi < 4; ++mi) af[mi] = *(const short8*)&As[(wm + mi * 16 + lr) * 32 + lk];
#pragma unroll
    for (int ni = 0; ni < 4; ++ni) bfr[ni] = *(const short8*)&Bs[(wn + ni * 16 + lr) * 32 + lk];
#pragma unroll
    for (int mi = 0; mi < 4; ++mi)
#pragma unroll
      for (int ni = 0; ni < 4; ++ni)
        acc[mi][ni] = __builtin_amdgcn_mfma_f32_16x16x32_bf16(af[mi], bfr[ni], acc[mi][ni], 0, 0, 0);
  }
#pragma unroll
  for (int mi = 0; mi < 4; ++mi) {
#pragma unroll
    for (int ni = 0; ni < 4; ++ni) {
      int col = tn0 + wn + ni * 16 + lr;
      float bval;
      if (EPI == 2) bval = (col < 3072) ? bias0[col] : bias1[col - 3072];
      else bval = bias0[col];
#pragma unroll
      for (int r = 0; r < 4; ++r) {
        int row = tm0 + wm + mi * 16 + (lane >> 4) * 4 + r;
        float v = acc[mi][ni][r] + bval;
        size_t idx = (size_t)row * ldo + col;
        if (EPI == 0 || EPI == 2) {
          ((unsigned short*)outp)[idx] = f2bf(v);
        } else if (EPI == 1) {
          if (row < Mvalid) ((float*)outp)[idx] = resid[idx] + v;
        } else {
          if (row < Mvalid) ((float*)outp)[idx] = ((float*)outp)[idx] + v;
        }
      }
    }
  }
}

// ---------------- RoPE in-place on qkv (bf16), q and k parts ----------------
__global__ __launch_bounds__(256) void rope_kernel(unsigned short* __restrict__ qkv,
                                                   const float* __restrict__ freqs) {
  int id = blockIdx.x * 256 + threadIdx.x;   // < M_*H_*32
  int e = id & 31;
  int hm = id >> 5;
  int head = hm % H_;
  int m = hm / H_;
  int n = m % N_;
  float f1 = freqs[n * HD_ + e];
  float f2 = freqs[n * HD_ + e + 32];
  float c1 = cosf(f1), s1 = sinf(f1);
  float c2 = cosf(f2), s2 = sinf(f2);
  unsigned short* base = qkv + (size_t)m * 2304 + head * HD_ + e;
#pragma unroll
  for (int part = 0; part < 2; ++part) {
    unsigned short* p = base + part * 768;
    float x1 = bf2f(p[0]);
    float x2 = bf2f(p[32]);
    p[0]  = f2bf(x1 * c1 - x2 * s1);
    p[32] = f2bf(x2 * c2 + x1 * s2);
  }
}

// ---------------- Attention v2: S^T trick, register-resident P ----------------
// Block = (b, head, 128 q rows), 4 waves; wave owns 32 q rows (2 subtiles of 16).
// QK^T computed as S^T = K·Q^T  (A=K frag -> D row=j, B=Q frag -> D col=m).
// C-layout of S^T == A-operand layout of 16x16x16 MFMA -> P feeds PV directly
// from registers (no LDS round-trip). PV in f16 (better mantissa than bf16).
__global__ __launch_bounds__(256, 2) void attn_kernel(
    const unsigned short* __restrict__ qkv,   // [MPAD_,2304] roped, bf16
    unsigned short* __restrict__ o2)          // [MPAD_,768]  bf16
{
  __shared__ __align__(16) unsigned short Ks[64 * 80];  // K rows, stride 80 (16B-aligned b128)
  __shared__ __align__(16) _Float16 Vt[64 * 72];        // V^T [d][j], stride 72
  int bidx = blockIdx.x;
  int qt = bidx % QT2_;
  int bh = bidx / QT2_;
  int head = bh % H_;
  int b = bh / H_;
  int t = threadIdx.x, lane = t & 63, wave = t >> 6;
  int lr = lane & 15, lg = lane >> 4;

  // Q fragments (B-operand): lane holds Q[m=lane&15][d = lg*8..+8 (+32 for half 1)]
  short8 bq[2][2];
#pragma unroll
  for (int s = 0; s < 2; ++s) {
    int m = qt * 128 + wave * 32 + s * 16 + lr;
    int mc = (m < N_) ? m : (N_ - 1);
    const unsigned short* qrow = qkv + (size_t)(b * N_ + mc) * 2304 + head * HD_;
    bq[s][0] = *(const short8*)(qrow + lg * 8);
    bq[s][1] = *(const short8*)(qrow + 32 + lg * 8);
  }

  f32x4 zero = {0.f, 0.f, 0.f, 0.f};
  f32x4 acc[2][4];
#pragma unroll
  for (int s = 0; s < 2; ++s)
#pragma unroll
    for (int dt = 0; dt < 4; ++dt) acc[s][dt] = zero;
  float den[2] = {0.f, 0.f};

  // V staging indices (fixed per thread)
  const int vp = t & 31;        // j-pair 0..31
  const int vc = t >> 5;        // d-chunk 0..7

  for (int jt = 0; jt < QT_; ++jt) {
    __syncthreads();
    // ---- stage K tile [64][64] -> Ks stride 80 (b128 writes, banks tile fully)
#pragma unroll
    for (int u = t; u < 512; u += 256) {
      int row = u >> 3, c = u & 7;
      int j = jt * 64 + row;
      int jc = (j < N_) ? j : (N_ - 1);
      const unsigned short* src = qkv + (size_t)(b * N_ + jc) * 2304 + 768 + head * HD_ + c * 8;
      *(short8*)&Ks[row * 80 + c * 8] = *(const short8*)src;
    }
    // ---- stage V^T [d][j] as f16, packed b32 writes (conflict-free: bank = (4i+p)%32)
    {
      int j0 = jt * 64 + 2 * vp;
      int j1 = j0 + 1;
      int j0c = (j0 < N_) ? j0 : (N_ - 1);
      int j1c = (j1 < N_) ? j1 : (N_ - 1);
      const unsigned short* s0 = qkv + (size_t)(b * N_ + j0c) * 2304 + 1536 + head * HD_ + vc * 8;
      const unsigned short* s1 = qkv + (size_t)(b * N_ + j1c) * 2304 + 1536 + head * HD_ + vc * 8;
      short8 v0 = *(const short8*)s0;
      short8 v1 = *(const short8*)s1;
#pragma unroll
      for (int i = 0; i < 8; ++i) {
        _Float16 lo = (_Float16)bf2f((unsigned short)v0[i]);
        _Float16 hi = (_Float16)bf2f((unsigned short)v1[i]);
        unsigned w = (unsigned)__builtin_bit_cast(unsigned short, lo)
                   | ((unsigned)__builtin_bit_cast(unsigned short, hi) << 16);
        *(unsigned*)&Vt[(vc * 8 + i) * 72 + 2 * vp] = w;
      }
    }
    __syncthreads();
    // ---- compute: 4 subtiles of 16 j
#pragma unroll
    for (int st = 0; st < 4; ++st) {
      short8 ak0 = *(const short8*)&Ks[(st * 16 + lr) * 80 + lg * 8];
      short8 ak1 = *(const short8*)&Ks[(st * 16 + lr) * 80 + 32 + lg * 8];
      int jb = jt * 64 + st * 16 + lg * 4;   // this lane's j base (rows of S^T)
      half4 pf[2];
#pragma unroll
      for (int s = 0; s < 2; ++s) {
        f32x4 sc = zero;
        sc = __builtin_amdgcn_mfma_f32_16x16x32_bf16(ak0, bq[s][0], sc, 0, 0, 0);
        sc = __builtin_amdgcn_mfma_f32_16x16x32_bf16(ak1, bq[s][1], sc, 0, 0, 0);
        float dsum = 0.f;
#pragma unroll
        for (int r = 0; r < 4; ++r) {
          float pv = (jb + r < N_) ? __expf(sc[r] * 0.125f) : 0.f;
          dsum += pv;
          pf[s][r] = (_Float16)pv;
        }
        den[s] += dsum;
      }
#pragma unroll
      for (int dt = 0; dt < 4; ++dt) {
        half4 bv = *(const half4*)&Vt[(dt * 16 + lr) * 72 + st * 16 + lg * 4];
        acc[0][dt] = __builtin_amdgcn_mfma_f32_16x16x16f16(pf[0], bv, acc[0][dt], 0, 0, 0);
        acc[1][dt] = __builtin_amdgcn_mfma_f32_16x16x16f16(pf[1], bv, acc[1][dt], 0, 0, 0);
      }
    }
  }
  // den currently per m=lane&15, partial over this quad's j subset -> sum quads
#pragma unroll
  for (int s = 0; s < 2; ++s) {
    den[s] += __shfl_xor(den[s], 16, 64);
    den[s] += __shfl_xor(den[s], 32, 64);
  }
  // epilogue: acc row = m_local = lg*4+r, col = dt*16+lr
#pragma unroll
  for (int s = 0; s < 2; ++s) {
#pragma unroll
    for (int r = 0; r < 4; ++r) {
      float dm = __shfl(den[s], lg * 4 + r, 64);   // lane with lane&15 == lg*4+r
      int m = qt * 128 + wave * 32 + s * 16 + lg * 4 + r;
      if (m < N_) {
        float invd = 1.f / dm;
        unsigned short* orow = o2 + (size_t)(b * N_ + m) * C_ + head * HD_;
#pragma unroll
        for (int dt = 0; dt < 4; ++dt)
          orow[dt * 16 + lr] = f2bf(acc[s][dt][r] * invd);
      }
    }
  }
}

// ---------------- SwiGLU: hid = silu(a1) * a2 ----------------
__global__ __launch_bounds__(256) void swiglu_kernel(const unsigned short* __restrict__ a12,
                                                     unsigned short* __restrict__ hid) {
  int id = blockIdx.x * 256 + threadIdx.x;   // < MPAD_*768
  int m = id / 768;
  int gj = id - m * 768;
  int j = gj * 4;
  const unsigned short* p1 = a12 + (size_t)m * 6144 + j;
  const unsigned short* p2 = p1 + 3072;
  ushort4 u1 = *(const ushort4*)p1;
  ushort4 u2 = *(const ushort4*)p2;
  float a0 = bf2f(u1.x), a1 = bf2f(u1.y), a2 = bf2f(u1.z), a3 = bf2f(u1.w);
  float b0 = bf2f(u2.x), b1 = bf2f(u2.y), b2 = bf2f(u2.z), b3 = bf2f(u2.w);
  ushort4 o;
  o.x = f2bf(a0 / (1.f + __expf(-a0)) * b0);
  o.y = f2bf(a1 / (1.f + __expf(-a1)) * b1);
  o.z = f2bf(a2 / (1.f + __expf(-a2)) * b2);
  o.w = f2bf(a3 / (1.f + __expf(-a3)) * b3);
  *(ushort4*)(hid + (size_t)m * 3072 + j) = o;
}

extern "C" void kernel_launch(void* const* d_in, const int* in_sizes, int n_in,
                              void* d_out, int out_size, void* d_ws, size_t ws_size,
                              hipStream_t stream) {
  const float* x      = (const float*)d_in[0];
  const float* freqs  = (const float*)d_in[1];
  const float* ln1_g  = (const float*)d_in[2];
  const float* ln1_b  = (const float*)d_in[3];
  const float* qkv_w  = (const float*)d_in[4];
  const float* qkv_b  = (const float*)d_in[5];
  const float* proj_w = (const float*)d_in[6];
  const float* proj_b = (const float*)d_in[7];
  const float* ln2_g  = (const float*)d_in[8];
  const float* ln2_b  = (const float*)d_in[9];
  const float* w1     = (const float*)d_in[10];
  const float* b1     = (const float*)d_in[11];
  const float* w2     = (const float*)d_in[12];
  const float* b2     = (const float*)d_in[13];
  const float* w3     = (const float*)d_in[14];
  const float* b3     = (const float*)d_in[15];
  float* out = (float*)d_out;
  char* ws = (char*)d_ws;

  // workspace layout (bytes)
  unsigned short* hB     = (unsigned short*)(ws + 0);          // [MPAD,768] bf16  16,908,288
  unsigned short* wqkvB  = (unsigned short*)(ws + 16908288);   // [2304,768]        3,538,944
  unsigned short* wprojB = (unsigned short*)(ws + 20447232);   // [768,768]         1,179,648
  unsigned short* w12B   = (unsigned short*)(ws + 21626880);   // [6144,768]        9,437,184
  unsigned short* w3B    = (unsigned short*)(ws + 31064064);   // [768,3072]        4,718,592
  unsigned short* qkvB   = (unsigned short*)(ws + 35782656);   // [MPAD,2304]      50,724,864
  unsigned short* o2B    = (unsigned short*)(ws + 86507520);   // [MPAD,768]       16,908,288
  unsigned short* a12B   = (unsigned short*)(ws + 103415808);  // [MPAD,6144]     135,266,304
  unsigned short* hidB   = qkvB;  // [MPAD,3072] overlaps dead qkv+o2

  // weights -> bf16
  cvt_kernel<<<1728, 256, 0, stream>>>(qkv_w, wqkvB, 2304 * 768 / 4);
  cvt_kernel<<<576,  256, 0, stream>>>(proj_w, wprojB, 768 * 768 / 4);
  cvt_kernel<<<2304, 256, 0, stream>>>(w1, w12B, 3072 * 768 / 4);
  cvt_kernel<<<2304, 256, 0, stream>>>(w2, w12B + 3072 * 768, 3072 * 768 / 4);
  cvt_kernel<<<2304, 256, 0, stream>>>(w3, w3B, 768 * 3072 / 4);

  // attention branch
  ln_kernel<<<M_, 256, 0, stream>>>(x, ln1_g, ln1_b, hB);
  gemm_bt<0><<<dim3(18, 86), 256, 0, stream>>>(hB, wqkvB, qkvB, qkv_b, nullptr, nullptr, 768, 2304, M_);
  rope_kernel<<<16488, 256, 0, stream>>>(qkvB, freqs);
  attn_kernel<<<B_ * H_ * QT2_, 256, 0, stream>>>(qkvB, o2B);
  gemm_bt<1><<<dim3(6, 86), 256, 0, stream>>>(o2B, wprojB, out, proj_b, nullptr, x, 768, 768, M_);

  // MLP branch
  ln_kernel<<<M_, 256, 0, stream>>>(out, ln2_g, ln2_b, hB);
  gemm_bt<2><<<dim3(48, 86), 256, 0, stream>>>(hB, w12B, a12B, b1, b2, nullptr, 768, 6144, M_);
  swiglu_kernel<<<33024, 256, 0, stream>>>(a12B, hidB);
  gemm_bt<3><<<dim3(6, 86), 256, 0, stream>>>(hidB, w3B, out, b3, nullptr, nullptr, 3072, 768, M_);
}

// Round 3
// 627.523 us; speedup vs baseline: 1.2848x; 1.1091x over previous
//
#include <hip/hip_runtime.h>
#include <stdint.h>

#define B_ 8
#define N_ 1374
#define C_ 768
#define H_ 12
#define HD_ 64
#define HID_ 3072
#define M_ (B_*N_)        // 10992
#define MPAD_ 11008       // 86 * 128
#define QT_ 22            // ceil(N/64)  (j tiles)
#define QT2_ 11           // ceil(N/128) (q tiles)

typedef __attribute__((ext_vector_type(8))) short short8;
typedef __attribute__((ext_vector_type(4))) float f32x4;
typedef __attribute__((ext_vector_type(4))) _Float16 half4;

__device__ __forceinline__ unsigned short f2bf(float f) {
  unsigned u = __float_as_uint(f);
  u += 0x7FFF + ((u >> 16) & 1);
  return (unsigned short)(u >> 16);
}
__device__ __forceinline__ float bf2f(unsigned short h) {
  return __uint_as_float(((unsigned)h) << 16);
}

#if __has_builtin(__builtin_amdgcn_global_load_lds)
#define HAVE_GLL 1
#endif

__device__ __forceinline__ void gld16(const unsigned short* g, unsigned short* l) {
#ifdef HAVE_GLL
  __builtin_amdgcn_global_load_lds((const __attribute__((address_space(1))) void*)g,
                                   (__attribute__((address_space(3))) void*)l, 16, 0, 0);
#else
  *(short8*)l = *(const short8*)g;
#endif
}

// ---------------- f32 -> bf16 conversion (weights) ----------------
__global__ __launch_bounds__(256) void cvt_kernel(const float* __restrict__ in,
                                                  unsigned short* __restrict__ out, int n4) {
  int id = blockIdx.x * 256 + threadIdx.x;
  if (id >= n4) return;
  float4 v = ((const float4*)in)[id];
  ushort4 o;
  o.x = f2bf(v.x); o.y = f2bf(v.y); o.z = f2bf(v.z); o.w = f2bf(v.w);
  ((ushort4*)out)[id] = o;
}

// ---------------- LayerNorm (f32 in, bf16 out) ----------------
__global__ __launch_bounds__(256) void ln_kernel(const float* __restrict__ in,
    const float* __restrict__ g, const float* __restrict__ bta,
    unsigned short* __restrict__ out) {
  int row = blockIdx.x;
  int t = threadIdx.x;
  const float* xr = in + (size_t)row * C_;
  float v0 = xr[t], v1 = xr[t + 256], v2 = xr[t + 512];
  float s1 = v0 + v1 + v2;
  float s2 = v0*v0 + v1*v1 + v2*v2;
  for (int off = 1; off < 64; off <<= 1) {
    s1 += __shfl_xor(s1, off, 64);
    s2 += __shfl_xor(s2, off, 64);
  }
  __shared__ float r1[4], r2[4];
  int wave = t >> 6, lane = t & 63;
  if (lane == 0) { r1[wave] = s1; r2[wave] = s2; }
  __syncthreads();
  float tot1 = r1[0] + r1[1] + r1[2] + r1[3];
  float tot2 = r2[0] + r2[1] + r2[2] + r2[3];
  float mu = tot1 * (1.0f / C_);
  float var = tot2 * (1.0f / C_) - mu * mu;
  float rs = rsqrtf(var + 1e-5f);
  size_t ob = (size_t)row * C_;
  out[ob + t]       = f2bf((v0 - mu) * rs * g[t]       + bta[t]);
  out[ob + t + 256] = f2bf((v1 - mu) * rs * g[t + 256] + bta[t + 256]);
  out[ob + t + 512] = f2bf((v2 - mu) * rs * g[t + 512] + bta[t + 512]);
}

// ---------------- GEMM: out[M,N] = A[M,K](bf16) * W[N,K]^T(bf16) + epilogue ----------------
// EPI 0: bf16 out + bias0           (qkv)
// EPI 1: f32 out = resid + v + bias (proj + residual), row-guarded
// EPI 3: f32 out += v + bias        (w3 + residual already in out), row-guarded
template<int EPI>
__global__ __launch_bounds__(256, 2) void gemm_bt(
    const unsigned short* __restrict__ A,
    const unsigned short* __restrict__ W,
    void* __restrict__ outp,
    const float* __restrict__ bias0,
    const float* __restrict__ resid,
    int K, int ldo, int Mvalid)
{
  __shared__ __align__(16) unsigned short As[4096];
  __shared__ __align__(16) unsigned short Bs[4096];
  const int t = threadIdx.x;
  const int lane = t & 63;
  const int wave = t >> 6;
  const int wm = (wave >> 1) * 64;
  const int wn = (wave & 1) * 64;
  const int lr = lane & 15;
  const int lk = (lane >> 4) * 8;
  const int tm0 = blockIdx.y * 128;
  const int tn0 = blockIdx.x * 128;
  const int r0 = t >> 2;
  const int c0 = (t & 3) * 8;
  const unsigned short* ga0 = A + (size_t)(tm0 + r0) * K + c0;
  const unsigned short* ga1 = A + (size_t)(tm0 + 64 + r0) * K + c0;
  const unsigned short* gb0 = W + (size_t)(tn0 + r0) * K + c0;
  const unsigned short* gb1 = W + (size_t)(tn0 + 64 + r0) * K + c0;
  f32x4 zero = {0.f, 0.f, 0.f, 0.f};
  f32x4 acc[4][4];
#pragma unroll
  for (int mi = 0; mi < 4; ++mi)
#pragma unroll
    for (int ni = 0; ni < 4; ++ni) acc[mi][ni] = zero;

  for (int kt = 0; kt < K; kt += 32) {
    __syncthreads();
    gld16(ga0 + kt, &As[t * 8]);
    gld16(ga1 + kt, &As[2048 + t * 8]);
    gld16(gb0 + kt, &Bs[t * 8]);
    gld16(gb1 + kt, &Bs[2048 + t * 8]);
    __syncthreads();
    short8 af[4], bfr[4];
#pragma unroll
    for (int mi = 0; mi < 4; ++mi) af[mi] = *(const short8*)&As[(wm + mi * 16 + lr) * 32 + lk];
#pragma unroll
    for (int ni = 0; ni < 4; ++ni) bfr[ni] = *(const short8*)&Bs[(wn + ni * 16 + lr) * 32 + lk];
#pragma unroll
    for (int mi = 0; mi < 4; ++mi)
#pragma unroll
      for (int ni = 0; ni < 4; ++ni)
        acc[mi][ni] = __builtin_amdgcn_mfma_f32_16x16x32_bf16(af[mi], bfr[ni], acc[mi][ni], 0, 0, 0);
  }
#pragma unroll
  for (int mi = 0; mi < 4; ++mi) {
#pragma unroll
    for (int ni = 0; ni < 4; ++ni) {
      int col = tn0 + wn + ni * 16 + lr;
      float bval = bias0[col];
#pragma unroll
      for (int r = 0; r < 4; ++r) {
        int row = tm0 + wm + mi * 16 + (lane >> 4) * 4 + r;
        float v = acc[mi][ni][r] + bval;
        size_t idx = (size_t)row * ldo + col;
        if (EPI == 0) {
          ((unsigned short*)outp)[idx] = f2bf(v);
        } else if (EPI == 1) {
          if (row < Mvalid) ((float*)outp)[idx] = resid[idx] + v;
        } else {
          if (row < Mvalid) ((float*)outp)[idx] = ((float*)outp)[idx] + v;
        }
      }
    }
  }
}

// ---------------- Fused GEMM: hid = silu(A*W1^T + b1) * (A*W2^T + b2) ----------------
// Block computes a 128x64 tile of hid. One shared A-tile, two 64x32 weight tiles.
// Per-K-iter profile identical to gemm_bt (4 gld16, 8 ds_read_b128, 16 MFMA).
__global__ __launch_bounds__(256, 2) void gemm_w12_swiglu(
    const unsigned short* __restrict__ A,     // [MPAD,768]
    const unsigned short* __restrict__ W1,    // [3072,768]
    const unsigned short* __restrict__ W2,    // [3072,768]
    unsigned short* __restrict__ hid,         // [MPAD,3072]
    const float* __restrict__ b1,
    const float* __restrict__ b2)
{
  __shared__ __align__(16) unsigned short As[4096];   // 128x32
  __shared__ __align__(16) unsigned short B1s[2048];  // 64x32
  __shared__ __align__(16) unsigned short B2s[2048];  // 64x32
  const int t = threadIdx.x;
  const int lane = t & 63;
  const int wave = t >> 6;
  const int wm = (wave >> 1) * 64;
  const int wn = (wave & 1) * 32;
  const int lr = lane & 15;
  const int lg = lane >> 4;
  const int lk = lg * 8;
  const int tm0 = blockIdx.y * 128;
  const int tn0 = blockIdx.x * 64;
  const int r0 = t >> 2;
  const int c0 = (t & 3) * 8;
  const unsigned short* ga0 = A + (size_t)(tm0 + r0) * 768 + c0;
  const unsigned short* ga1 = A + (size_t)(tm0 + 64 + r0) * 768 + c0;
  const unsigned short* g1 = W1 + (size_t)(tn0 + r0) * 768 + c0;
  const unsigned short* g2 = W2 + (size_t)(tn0 + r0) * 768 + c0;
  f32x4 zero = {0.f, 0.f, 0.f, 0.f};
  f32x4 acc1[4][2], acc2[4][2];
#pragma unroll
  for (int mi = 0; mi < 4; ++mi)
#pragma unroll
    for (int ni = 0; ni < 2; ++ni) { acc1[mi][ni] = zero; acc2[mi][ni] = zero; }

  for (int kt = 0; kt < 768; kt += 32) {
    __syncthreads();
    gld16(ga0 + kt, &As[t * 8]);
    gld16(ga1 + kt, &As[2048 + t * 8]);
    gld16(g1 + kt, &B1s[t * 8]);
    gld16(g2 + kt, &B2s[t * 8]);
    __syncthreads();
    short8 af[4], b1f[2], b2f[2];
#pragma unroll
    for (int mi = 0; mi < 4; ++mi) af[mi] = *(const short8*)&As[(wm + mi * 16 + lr) * 32 + lk];
#pragma unroll
    for (int ni = 0; ni < 2; ++ni) {
      b1f[ni] = *(const short8*)&B1s[(wn + ni * 16 + lr) * 32 + lk];
      b2f[ni] = *(const short8*)&B2s[(wn + ni * 16 + lr) * 32 + lk];
    }
#pragma unroll
    for (int mi = 0; mi < 4; ++mi)
#pragma unroll
      for (int ni = 0; ni < 2; ++ni) {
        acc1[mi][ni] = __builtin_amdgcn_mfma_f32_16x16x32_bf16(af[mi], b1f[ni], acc1[mi][ni], 0, 0, 0);
        acc2[mi][ni] = __builtin_amdgcn_mfma_f32_16x16x32_bf16(af[mi], b2f[ni], acc2[mi][ni], 0, 0, 0);
      }
  }
#pragma unroll
  for (int mi = 0; mi < 4; ++mi) {
#pragma unroll
    for (int ni = 0; ni < 2; ++ni) {
      int col = tn0 + wn + ni * 16 + lr;
      float bv1 = b1[col], bv2 = b2[col];
#pragma unroll
      for (int r = 0; r < 4; ++r) {
        int row = tm0 + wm + mi * 16 + lg * 4 + r;
        float a1 = acc1[mi][ni][r] + bv1;
        float a2 = acc2[mi][ni][r] + bv2;
        float h = a1 / (1.f + __expf(-a1)) * a2;
        hid[(size_t)row * HID_ + col] = f2bf(h);
      }
    }
  }
}

// ---------------- RoPE in-place on qkv (bf16), q and k parts ----------------
__global__ __launch_bounds__(256) void rope_kernel(unsigned short* __restrict__ qkv,
                                                   const float* __restrict__ freqs) {
  int id = blockIdx.x * 256 + threadIdx.x;   // < M_*H_*32
  int e = id & 31;
  int hm = id >> 5;
  int head = hm % H_;
  int m = hm / H_;
  int n = m % N_;
  float f1 = freqs[n * HD_ + e];
  float f2 = freqs[n * HD_ + e + 32];
  float c1 = cosf(f1), s1 = sinf(f1);
  float c2 = cosf(f2), s2 = sinf(f2);
  unsigned short* base = qkv + (size_t)m * 2304 + head * HD_ + e;
#pragma unroll
  for (int part = 0; part < 2; ++part) {
    unsigned short* p = base + part * 768;
    float x1 = bf2f(p[0]);
    float x2 = bf2f(p[32]);
    p[0]  = f2bf(x1 * c1 - x2 * s1);
    p[32] = f2bf(x2 * c2 + x1 * s2);
  }
}

// ---------------- Attention v2: S^T trick, register-resident P ----------------
__global__ __launch_bounds__(256, 2) void attn_kernel(
    const unsigned short* __restrict__ qkv,   // [MPAD_,2304] roped, bf16
    unsigned short* __restrict__ o2)          // [MPAD_,768]  bf16
{
  __shared__ __align__(16) unsigned short Ks[64 * 80];  // K rows, stride 80
  __shared__ __align__(16) _Float16 Vt[64 * 72];        // V^T [d][j], stride 72
  int bidx = blockIdx.x;
  int qt = bidx % QT2_;
  int bh = bidx / QT2_;
  int head = bh % H_;
  int b = bh / H_;
  int t = threadIdx.x, lane = t & 63, wave = t >> 6;
  int lr = lane & 15, lg = lane >> 4;

  short8 bq[2][2];
#pragma unroll
  for (int s = 0; s < 2; ++s) {
    int m = qt * 128 + wave * 32 + s * 16 + lr;
    int mc = (m < N_) ? m : (N_ - 1);
    const unsigned short* qrow = qkv + (size_t)(b * N_ + mc) * 2304 + head * HD_;
    bq[s][0] = *(const short8*)(qrow + lg * 8);
    bq[s][1] = *(const short8*)(qrow + 32 + lg * 8);
  }

  f32x4 zero = {0.f, 0.f, 0.f, 0.f};
  f32x4 acc[2][4];
#pragma unroll
  for (int s = 0; s < 2; ++s)
#pragma unroll
    for (int dt = 0; dt < 4; ++dt) acc[s][dt] = zero;
  float den[2] = {0.f, 0.f};

  const int vp = t & 31;        // j-pair 0..31
  const int vc = t >> 5;        // d-chunk 0..7

  for (int jt = 0; jt < QT_; ++jt) {
    __syncthreads();
#pragma unroll
    for (int u = t; u < 512; u += 256) {
      int row = u >> 3, c = u & 7;
      int j = jt * 64 + row;
      int jc = (j < N_) ? j : (N_ - 1);
      const unsigned short* src = qkv + (size_t)(b * N_ + jc) * 2304 + 768 + head * HD_ + c * 8;
      *(short8*)&Ks[row * 80 + c * 8] = *(const short8*)src;
    }
    {
      int j0 = jt * 64 + 2 * vp;
      int j1 = j0 + 1;
      int j0c = (j0 < N_) ? j0 : (N_ - 1);
      int j1c = (j1 < N_) ? j1 : (N_ - 1);
      const unsigned short* s0 = qkv + (size_t)(b * N_ + j0c) * 2304 + 1536 + head * HD_ + vc * 8;
      const unsigned short* s1 = qkv + (size_t)(b * N_ + j1c) * 2304 + 1536 + head * HD_ + vc * 8;
      short8 v0 = *(const short8*)s0;
      short8 v1 = *(const short8*)s1;
#pragma unroll
      for (int i = 0; i < 8; ++i) {
        _Float16 lo = (_Float16)bf2f((unsigned short)v0[i]);
        _Float16 hi = (_Float16)bf2f((unsigned short)v1[i]);
        unsigned w = (unsigned)__builtin_bit_cast(unsigned short, lo)
                   | ((unsigned)__builtin_bit_cast(unsigned short, hi) << 16);
        *(unsigned*)&Vt[(vc * 8 + i) * 72 + 2 * vp] = w;
      }
    }
    __syncthreads();
#pragma unroll
    for (int st = 0; st < 4; ++st) {
      short8 ak0 = *(const short8*)&Ks[(st * 16 + lr) * 80 + lg * 8];
      short8 ak1 = *(const short8*)&Ks[(st * 16 + lr) * 80 + 32 + lg * 8];
      int jb = jt * 64 + st * 16 + lg * 4;
      half4 pf[2];
#pragma unroll
      for (int s = 0; s < 2; ++s) {
        f32x4 sc = zero;
        sc = __builtin_amdgcn_mfma_f32_16x16x32_bf16(ak0, bq[s][0], sc, 0, 0, 0);
        sc = __builtin_amdgcn_mfma_f32_16x16x32_bf16(ak1, bq[s][1], sc, 0, 0, 0);
        float dsum = 0.f;
#pragma unroll
        for (int r = 0; r < 4; ++r) {
          float pv = (jb + r < N_) ? __expf(sc[r] * 0.125f) : 0.f;
          dsum += pv;
          pf[s][r] = (_Float16)pv;
        }
        den[s] += dsum;
      }
#pragma unroll
      for (int dt = 0; dt < 4; ++dt) {
        half4 bv = *(const half4*)&Vt[(dt * 16 + lr) * 72 + st * 16 + lg * 4];
        acc[0][dt] = __builtin_amdgcn_mfma_f32_16x16x16f16(pf[0], bv, acc[0][dt], 0, 0, 0);
        acc[1][dt] = __builtin_amdgcn_mfma_f32_16x16x16f16(pf[1], bv, acc[1][dt], 0, 0, 0);
      }
    }
  }
#pragma unroll
  for (int s = 0; s < 2; ++s) {
    den[s] += __shfl_xor(den[s], 16, 64);
    den[s] += __shfl_xor(den[s], 32, 64);
  }
#pragma unroll
  for (int s = 0; s < 2; ++s) {
#pragma unroll
    for (int r = 0; r < 4; ++r) {
      float dm = __shfl(den[s], lg * 4 + r, 64);
      int m = qt * 128 + wave * 32 + s * 16 + lg * 4 + r;
      if (m < N_) {
        float invd = 1.f / dm;
        unsigned short* orow = o2 + (size_t)(b * N_ + m) * C_ + head * HD_;
#pragma unroll
        for (int dt = 0; dt < 4; ++dt)
          orow[dt * 16 + lr] = f2bf(acc[s][dt][r] * invd);
      }
    }
  }
}

extern "C" void kernel_launch(void* const* d_in, const int* in_sizes, int n_in,
                              void* d_out, int out_size, void* d_ws, size_t ws_size,
                              hipStream_t stream) {
  const float* x      = (const float*)d_in[0];
  const float* freqs  = (const float*)d_in[1];
  const float* ln1_g  = (const float*)d_in[2];
  const float* ln1_b  = (const float*)d_in[3];
  const float* qkv_w  = (const float*)d_in[4];
  const float* qkv_b  = (const float*)d_in[5];
  const float* proj_w = (const float*)d_in[6];
  const float* proj_b = (const float*)d_in[7];
  const float* ln2_g  = (const float*)d_in[8];
  const float* ln2_b  = (const float*)d_in[9];
  const float* w1     = (const float*)d_in[10];
  const float* b1     = (const float*)d_in[11];
  const float* w2     = (const float*)d_in[12];
  const float* b2     = (const float*)d_in[13];
  const float* w3     = (const float*)d_in[14];
  const float* b3     = (const float*)d_in[15];
  float* out = (float*)d_out;
  char* ws = (char*)d_ws;

  // workspace layout (bytes)
  unsigned short* hB     = (unsigned short*)(ws + 0);          // [MPAD,768] bf16  16,908,288
  unsigned short* wqkvB  = (unsigned short*)(ws + 16908288);   // [2304,768]        3,538,944
  unsigned short* wprojB = (unsigned short*)(ws + 20447232);   // [768,768]         1,179,648
  unsigned short* w12B   = (unsigned short*)(ws + 21626880);   // [6144,768]        9,437,184
  unsigned short* w3B    = (unsigned short*)(ws + 31064064);   // [768,3072]        4,718,592
  unsigned short* qkvB   = (unsigned short*)(ws + 35782656);   // [MPAD,2304]      50,724,864
  unsigned short* o2B    = (unsigned short*)(ws + 86507520);   // [MPAD,768]       16,908,288
  unsigned short* hidB   = qkvB;  // [MPAD,3072] overlaps dead qkv+o2 after proj

  // weights -> bf16
  cvt_kernel<<<1728, 256, 0, stream>>>(qkv_w, wqkvB, 2304 * 768 / 4);
  cvt_kernel<<<576,  256, 0, stream>>>(proj_w, wprojB, 768 * 768 / 4);
  cvt_kernel<<<2304, 256, 0, stream>>>(w1, w12B, 3072 * 768 / 4);
  cvt_kernel<<<2304, 256, 0, stream>>>(w2, w12B + 3072 * 768, 3072 * 768 / 4);
  cvt_kernel<<<2304, 256, 0, stream>>>(w3, w3B, 768 * 3072 / 4);

  // attention branch
  ln_kernel<<<M_, 256, 0, stream>>>(x, ln1_g, ln1_b, hB);
  gemm_bt<0><<<dim3(18, 86), 256, 0, stream>>>(hB, wqkvB, qkvB, qkv_b, nullptr, 768, 2304, M_);
  rope_kernel<<<16488, 256, 0, stream>>>(qkvB, freqs);
  attn_kernel<<<B_ * H_ * QT2_, 256, 0, stream>>>(qkvB, o2B);
  gemm_bt<1><<<dim3(6, 86), 256, 0, stream>>>(o2B, wprojB, out, proj_b, x, 768, 768, M_);

  // MLP branch (fused w1|w2 + swiglu -> hid, then w3 + residual)
  ln_kernel<<<M_, 256, 0, stream>>>(out, ln2_g, ln2_b, hB);
  gemm_w12_swiglu<<<dim3(48, 86), 256, 0, stream>>>(hB, w12B, w12B + 3072 * 768, hidB, b1, b2);
  gemm_bt<3><<<dim3(6, 86), 256, 0, stream>>>(hidB, w3B, out, b3, nullptr, 3072, 768, M_);
}

// Round 4
// 598.663 us; speedup vs baseline: 1.3468x; 1.0482x over previous
//
#include <hip/hip_runtime.h>
#include <stdint.h>

#define B_ 8
#define N_ 1374
#define C_ 768
#define H_ 12
#define HD_ 64
#define HID_ 3072
#define M_ (B_*N_)        // 10992
#define MPAD_ 11008       // 86 * 128
#define QT_ 22            // ceil(N/64)  (j tiles)
#define QT2_ 11           // ceil(N/128) (q tiles)

typedef __attribute__((ext_vector_type(8))) short short8;
typedef __attribute__((ext_vector_type(4))) float f32x4;
typedef __attribute__((ext_vector_type(4))) _Float16 half4;

__device__ __forceinline__ unsigned short f2bf(float f) {
  unsigned u = __float_as_uint(f);
  u += 0x7FFF + ((u >> 16) & 1);
  return (unsigned short)(u >> 16);
}
__device__ __forceinline__ float bf2f(unsigned short h) {
  return __uint_as_float(((unsigned)h) << 16);
}

#if __has_builtin(__builtin_amdgcn_global_load_lds)
#define HAVE_GLL 1
#endif

__device__ __forceinline__ void gld16(const unsigned short* g, unsigned short* l) {
#ifdef HAVE_GLL
  __builtin_amdgcn_global_load_lds((const __attribute__((address_space(1))) void*)g,
                                   (__attribute__((address_space(3))) void*)l, 16, 0, 0);
#else
  *(short8*)l = *(const short8*)g;
#endif
}

// ---------------- single fused f32 -> bf16 conversion for all 5 weights ----------------
// dest is one contiguous bf16 block: [qkv_w | proj_w | w1 | w2 | w3]
__global__ __launch_bounds__(256) void cvt5_kernel(
    const float* __restrict__ s0, const float* __restrict__ s1,
    const float* __restrict__ s2, const float* __restrict__ s3,
    const float* __restrict__ s4, unsigned short* __restrict__ out) {
  int id = blockIdx.x * 256 + threadIdx.x;   // float4 index, grid covers exactly 2359296
  const float* src; int off;
  if (id < 442368)        { src = s0; off = id; }
  else if (id < 589824)   { src = s1; off = id - 442368; }
  else if (id < 1179648)  { src = s2; off = id - 589824; }
  else if (id < 1769472)  { src = s3; off = id - 1179648; }
  else                    { src = s4; off = id - 1769472; }
  float4 v = ((const float4*)src)[off];
  ushort4 o;
  o.x = f2bf(v.x); o.y = f2bf(v.y); o.z = f2bf(v.z); o.w = f2bf(v.w);
  ((ushort4*)out)[id] = o;
}

// ---------------- LayerNorm (f32 in, bf16 out) ----------------
__global__ __launch_bounds__(256) void ln_kernel(const float* __restrict__ in,
    const float* __restrict__ g, const float* __restrict__ bta,
    unsigned short* __restrict__ out) {
  int row = blockIdx.x;
  int t = threadIdx.x;
  const float* xr = in + (size_t)row * C_;
  float v0 = xr[t], v1 = xr[t + 256], v2 = xr[t + 512];
  float s1 = v0 + v1 + v2;
  float s2 = v0*v0 + v1*v1 + v2*v2;
  for (int off = 1; off < 64; off <<= 1) {
    s1 += __shfl_xor(s1, off, 64);
    s2 += __shfl_xor(s2, off, 64);
  }
  __shared__ float r1[4], r2[4];
  int wave = t >> 6, lane = t & 63;
  if (lane == 0) { r1[wave] = s1; r2[wave] = s2; }
  __syncthreads();
  float tot1 = r1[0] + r1[1] + r1[2] + r1[3];
  float tot2 = r2[0] + r2[1] + r2[2] + r2[3];
  float mu = tot1 * (1.0f / C_);
  float var = tot2 * (1.0f / C_) - mu * mu;
  float rs = rsqrtf(var + 1e-5f);
  size_t ob = (size_t)row * C_;
  out[ob + t]       = f2bf((v0 - mu) * rs * g[t]       + bta[t]);
  out[ob + t + 256] = f2bf((v1 - mu) * rs * g[t + 256] + bta[t + 256]);
  out[ob + t + 512] = f2bf((v2 - mu) * rs * g[t + 512] + bta[t + 512]);
}

// ---------------- GEMM: out[M,N] = A[M,K](bf16) * W[N,K]^T(bf16) + epilogue ----------------
// BK=64 via two stride-32 half-K LDS buffers (keeps gld16-legal packed layout AND
// the proven 8-bank-quad ds_read_b128 spread; halves barrier count vs BK=32).
// EPI 0: bf16 out + bias0 (+ optional fused RoPE on q,k windows)   (qkv)
// EPI 1: f32 out = resid + v + bias (proj + residual), row-guarded
// EPI 3: f32 out += v + bias        (w3 + residual already in out), row-guarded
template<int EPI, int ROPE>
__global__ __launch_bounds__(256, 2) void gemm_bt(
    const unsigned short* __restrict__ A,
    const unsigned short* __restrict__ W,
    void* __restrict__ outp,
    const float* __restrict__ bias0,
    const float* __restrict__ resid,
    const float* __restrict__ freqs,
    int K, int ldo, int Mvalid)
{
  __shared__ __align__(16) unsigned short As[2][4096];
  __shared__ __align__(16) unsigned short Bs[2][4096];
  const int t = threadIdx.x;
  const int lane = t & 63;
  const int wave = t >> 6;
  const int wm = (wave >> 1) * 64;
  const int wn = (wave & 1) * 64;
  const int lr = lane & 15;
  const int lg = lane >> 4;
  const int lk = lg * 8;
  const int tm0 = blockIdx.y * 128;
  const int tn0 = blockIdx.x * 128;
  const int r0 = t >> 2;
  const int c0 = (t & 3) * 8;
  const unsigned short* ga0 = A + (size_t)(tm0 + r0) * K + c0;
  const unsigned short* ga1 = A + (size_t)(tm0 + 64 + r0) * K + c0;
  const unsigned short* gb0 = W + (size_t)(tn0 + r0) * K + c0;
  const unsigned short* gb1 = W + (size_t)(tn0 + 64 + r0) * K + c0;
  f32x4 zero = {0.f, 0.f, 0.f, 0.f};
  f32x4 acc[4][4];
#pragma unroll
  for (int mi = 0; mi < 4; ++mi)
#pragma unroll
    for (int ni = 0; ni < 4; ++ni) acc[mi][ni] = zero;

  for (int kt = 0; kt < K; kt += 64) {
    __syncthreads();
    gld16(ga0 + kt,      &As[0][t * 8]);
    gld16(ga1 + kt,      &As[0][2048 + t * 8]);
    gld16(ga0 + kt + 32, &As[1][t * 8]);
    gld16(ga1 + kt + 32, &As[1][2048 + t * 8]);
    gld16(gb0 + kt,      &Bs[0][t * 8]);
    gld16(gb1 + kt,      &Bs[0][2048 + t * 8]);
    gld16(gb0 + kt + 32, &Bs[1][t * 8]);
    gld16(gb1 + kt + 32, &Bs[1][2048 + t * 8]);
    __syncthreads();
#pragma unroll
    for (int u = 0; u < 2; ++u) {
      short8 af[4], bfr[4];
#pragma unroll
      for (int mi = 0; mi < 4; ++mi) af[mi] = *(const short8*)&As[u][(wm + mi * 16 + lr) * 32 + lk];
#pragma unroll
      for (int ni = 0; ni < 4; ++ni) bfr[ni] = *(const short8*)&Bs[u][(wn + ni * 16 + lr) * 32 + lk];
#pragma unroll
      for (int mi = 0; mi < 4; ++mi)
#pragma unroll
        for (int ni = 0; ni < 4; ++ni)
          acc[mi][ni] = __builtin_amdgcn_mfma_f32_16x16x32_bf16(af[mi], bfr[ni], acc[mi][ni], 0, 0, 0);
    }
  }

  if (EPI == 0) {
    // paired epilogue (cols e and e+32 of a 64-aligned window) for fused RoPE
    bool dorope = ROPE && ((tn0 + wn) < 1536);   // q,k windows only; wave-uniform
#pragma unroll
    for (int mi = 0; mi < 4; ++mi) {
#pragma unroll
      for (int p = 0; p < 2; ++p) {
        int col1 = tn0 + wn + p * 16 + lr;
        int col2 = col1 + 32;
        float bv1 = bias0[col1], bv2 = bias0[col2];
        int e = p * 16 + lr;
#pragma unroll
        for (int r = 0; r < 4; ++r) {
          int row = tm0 + wm + mi * 16 + lg * 4 + r;
          float v1 = acc[mi][p][r] + bv1;
          float v2 = acc[mi][p + 2][r] + bv2;
          float o1 = v1, o2 = v2;
          if (dorope) {
            int n = row % N_;
            float f1 = freqs[n * HD_ + e];
            float f2 = freqs[n * HD_ + e + 32];
            float c1, s1, c2, s2;
            __sincosf(f1, &s1, &c1);
            __sincosf(f2, &s2, &c2);
            o1 = v1 * c1 - v2 * s1;
            o2 = v2 * c2 + v1 * s2;
          }
          size_t base = (size_t)row * ldo;
          ((unsigned short*)outp)[base + col1] = f2bf(o1);
          ((unsigned short*)outp)[base + col2] = f2bf(o2);
        }
      }
    }
  } else {
#pragma unroll
    for (int mi = 0; mi < 4; ++mi) {
#pragma unroll
      for (int ni = 0; ni < 4; ++ni) {
        int col = tn0 + wn + ni * 16 + lr;
        float bval = bias0[col];
#pragma unroll
        for (int r = 0; r < 4; ++r) {
          int row = tm0 + wm + mi * 16 + lg * 4 + r;
          float v = acc[mi][ni][r] + bval;
          size_t idx = (size_t)row * ldo + col;
          if (EPI == 1) {
            if (row < Mvalid) ((float*)outp)[idx] = resid[idx] + v;
          } else {
            if (row < Mvalid) ((float*)outp)[idx] = ((float*)outp)[idx] + v;
          }
        }
      }
    }
  }
}

// ---------------- Fused GEMM: hid = silu(A*W1^T + b1) * (A*W2^T + b2), BK=64 ----------------
__global__ __launch_bounds__(256, 2) void gemm_w12_swiglu(
    const unsigned short* __restrict__ A,     // [MPAD,768]
    const unsigned short* __restrict__ W1,    // [3072,768]
    const unsigned short* __restrict__ W2,    // [3072,768]
    unsigned short* __restrict__ hid,         // [MPAD,3072]
    const float* __restrict__ b1,
    const float* __restrict__ b2)
{
  __shared__ __align__(16) unsigned short As[2][4096];   // 128x32 per half-K
  __shared__ __align__(16) unsigned short B1s[2][2048];  // 64x32 per half-K
  __shared__ __align__(16) unsigned short B2s[2][2048];
  const int t = threadIdx.x;
  const int lane = t & 63;
  const int wave = t >> 6;
  const int wm = (wave >> 1) * 64;
  const int wn = (wave & 1) * 32;
  const int lr = lane & 15;
  const int lg = lane >> 4;
  const int lk = lg * 8;
  const int tm0 = blockIdx.y * 128;
  const int tn0 = blockIdx.x * 64;
  const int r0 = t >> 2;
  const int c0 = (t & 3) * 8;
  const unsigned short* ga0 = A + (size_t)(tm0 + r0) * 768 + c0;
  const unsigned short* ga1 = A + (size_t)(tm0 + 64 + r0) * 768 + c0;
  const unsigned short* g1 = W1 + (size_t)(tn0 + r0) * 768 + c0;
  const unsigned short* g2 = W2 + (size_t)(tn0 + r0) * 768 + c0;
  f32x4 zero = {0.f, 0.f, 0.f, 0.f};
  f32x4 acc1[4][2], acc2[4][2];
#pragma unroll
  for (int mi = 0; mi < 4; ++mi)
#pragma unroll
    for (int ni = 0; ni < 2; ++ni) { acc1[mi][ni] = zero; acc2[mi][ni] = zero; }

  for (int kt = 0; kt < 768; kt += 64) {
    __syncthreads();
    gld16(ga0 + kt,      &As[0][t * 8]);
    gld16(ga1 + kt,      &As[0][2048 + t * 8]);
    gld16(ga0 + kt + 32, &As[1][t * 8]);
    gld16(ga1 + kt + 32, &As[1][2048 + t * 8]);
    gld16(g1 + kt,       &B1s[0][t * 8]);
    gld16(g1 + kt + 32,  &B1s[1][t * 8]);
    gld16(g2 + kt,       &B2s[0][t * 8]);
    gld16(g2 + kt + 32,  &B2s[1][t * 8]);
    __syncthreads();
#pragma unroll
    for (int u = 0; u < 2; ++u) {
      short8 af[4], b1f[2], b2f[2];
#pragma unroll
      for (int mi = 0; mi < 4; ++mi) af[mi] = *(const short8*)&As[u][(wm + mi * 16 + lr) * 32 + lk];
#pragma unroll
      for (int ni = 0; ni < 2; ++ni) {
        b1f[ni] = *(const short8*)&B1s[u][(wn + ni * 16 + lr) * 32 + lk];
        b2f[ni] = *(const short8*)&B2s[u][(wn + ni * 16 + lr) * 32 + lk];
      }
#pragma unroll
      for (int mi = 0; mi < 4; ++mi)
#pragma unroll
        for (int ni = 0; ni < 2; ++ni) {
          acc1[mi][ni] = __builtin_amdgcn_mfma_f32_16x16x32_bf16(af[mi], b1f[ni], acc1[mi][ni], 0, 0, 0);
          acc2[mi][ni] = __builtin_amdgcn_mfma_f32_16x16x32_bf16(af[mi], b2f[ni], acc2[mi][ni], 0, 0, 0);
        }
    }
  }
#pragma unroll
  for (int mi = 0; mi < 4; ++mi) {
#pragma unroll
    for (int ni = 0; ni < 2; ++ni) {
      int col = tn0 + wn + ni * 16 + lr;
      float bv1 = b1[col], bv2 = b2[col];
#pragma unroll
      for (int r = 0; r < 4; ++r) {
        int row = tm0 + wm + mi * 16 + lg * 4 + r;
        float a1 = acc1[mi][ni][r] + bv1;
        float a2 = acc2[mi][ni][r] + bv2;
        float h = a1 / (1.f + __expf(-a1)) * a2;
        hid[(size_t)row * HID_ + col] = f2bf(h);
      }
    }
  }
}

// ---------------- Attention v2: S^T trick, register-resident P ----------------
__global__ __launch_bounds__(256, 2) void attn_kernel(
    const unsigned short* __restrict__ qkv,   // [MPAD_,2304] roped, bf16
    unsigned short* __restrict__ o2)          // [MPAD_,768]  bf16
{
  __shared__ __align__(16) unsigned short Ks[64 * 80];  // K rows, stride 80
  __shared__ __align__(16) _Float16 Vt[64 * 72];        // V^T [d][j], stride 72
  int bidx = blockIdx.x;
  int qt = bidx % QT2_;
  int bh = bidx / QT2_;
  int head = bh % H_;
  int b = bh / H_;
  int t = threadIdx.x, lane = t & 63, wave = t >> 6;
  int lr = lane & 15, lg = lane >> 4;

  short8 bq[2][2];
#pragma unroll
  for (int s = 0; s < 2; ++s) {
    int m = qt * 128 + wave * 32 + s * 16 + lr;
    int mc = (m < N_) ? m : (N_ - 1);
    const unsigned short* qrow = qkv + (size_t)(b * N_ + mc) * 2304 + head * HD_;
    bq[s][0] = *(const short8*)(qrow + lg * 8);
    bq[s][1] = *(const short8*)(qrow + 32 + lg * 8);
  }

  f32x4 zero = {0.f, 0.f, 0.f, 0.f};
  f32x4 acc[2][4];
#pragma unroll
  for (int s = 0; s < 2; ++s)
#pragma unroll
    for (int dt = 0; dt < 4; ++dt) acc[s][dt] = zero;
  float den[2] = {0.f, 0.f};

  const int vp = t & 31;        // j-pair 0..31
  const int vc = t >> 5;        // d-chunk 0..7

  for (int jt = 0; jt < QT_; ++jt) {
    __syncthreads();
#pragma unroll
    for (int u = t; u < 512; u += 256) {
      int row = u >> 3, c = u & 7;
      int j = jt * 64 + row;
      int jc = (j < N_) ? j : (N_ - 1);
      const unsigned short* src = qkv + (size_t)(b * N_ + jc) * 2304 + 768 + head * HD_ + c * 8;
      *(short8*)&Ks[row * 80 + c * 8] = *(const short8*)src;
    }
    {
      int j0 = jt * 64 + 2 * vp;
      int j1 = j0 + 1;
      int j0c = (j0 < N_) ? j0 : (N_ - 1);
      int j1c = (j1 < N_) ? j1 : (N_ - 1);
      const unsigned short* s0 = qkv + (size_t)(b * N_ + j0c) * 2304 + 1536 + head * HD_ + vc * 8;
      const unsigned short* s1 = qkv + (size_t)(b * N_ + j1c) * 2304 + 1536 + head * HD_ + vc * 8;
      short8 v0 = *(const short8*)s0;
      short8 v1 = *(const short8*)s1;
#pragma unroll
      for (int i = 0; i < 8; ++i) {
        _Float16 lo = (_Float16)bf2f((unsigned short)v0[i]);
        _Float16 hi = (_Float16)bf2f((unsigned short)v1[i]);
        unsigned w = (unsigned)__builtin_bit_cast(unsigned short, lo)
                   | ((unsigned)__builtin_bit_cast(unsigned short, hi) << 16);
        *(unsigned*)&Vt[(vc * 8 + i) * 72 + 2 * vp] = w;
      }
    }
    __syncthreads();
#pragma unroll
    for (int st = 0; st < 4; ++st) {
      short8 ak0 = *(const short8*)&Ks[(st * 16 + lr) * 80 + lg * 8];
      short8 ak1 = *(const short8*)&Ks[(st * 16 + lr) * 80 + 32 + lg * 8];
      int jb = jt * 64 + st * 16 + lg * 4;
      half4 pf[2];
#pragma unroll
      for (int s = 0; s < 2; ++s) {
        f32x4 sc = zero;
        sc = __builtin_amdgcn_mfma_f32_16x16x32_bf16(ak0, bq[s][0], sc, 0, 0, 0);
        sc = __builtin_amdgcn_mfma_f32_16x16x32_bf16(ak1, bq[s][1], sc, 0, 0, 0);
        float dsum = 0.f;
#pragma unroll
        for (int r = 0; r < 4; ++r) {
          float pv = (jb + r < N_) ? __expf(sc[r] * 0.125f) : 0.f;
          dsum += pv;
          pf[s][r] = (_Float16)pv;
        }
        den[s] += dsum;
      }
#pragma unroll
      for (int dt = 0; dt < 4; ++dt) {
        half4 bv = *(const half4*)&Vt[(dt * 16 + lr) * 72 + st * 16 + lg * 4];
        acc[0][dt] = __builtin_amdgcn_mfma_f32_16x16x16f16(pf[0], bv, acc[0][dt], 0, 0, 0);
        acc[1][dt] = __builtin_amdgcn_mfma_f32_16x16x16f16(pf[1], bv, acc[1][dt], 0, 0, 0);
      }
    }
  }
#pragma unroll
  for (int s = 0; s < 2; ++s) {
    den[s] += __shfl_xor(den[s], 16, 64);
    den[s] += __shfl_xor(den[s], 32, 64);
  }
#pragma unroll
  for (int s = 0; s < 2; ++s) {
#pragma unroll
    for (int r = 0; r < 4; ++r) {
      float dm = __shfl(den[s], lg * 4 + r, 64);
      int m = qt * 128 + wave * 32 + s * 16 + lg * 4 + r;
      if (m < N_) {
        float invd = 1.f / dm;
        unsigned short* orow = o2 + (size_t)(b * N_ + m) * C_ + head * HD_;
#pragma unroll
        for (int dt = 0; dt < 4; ++dt)
          orow[dt * 16 + lr] = f2bf(acc[s][dt][r] * invd);
      }
    }
  }
}

extern "C" void kernel_launch(void* const* d_in, const int* in_sizes, int n_in,
                              void* d_out, int out_size, void* d_ws, size_t ws_size,
                              hipStream_t stream) {
  const float* x      = (const float*)d_in[0];
  const float* freqs  = (const float*)d_in[1];
  const float* ln1_g  = (const float*)d_in[2];
  const float* ln1_b  = (const float*)d_in[3];
  const float* qkv_w  = (const float*)d_in[4];
  const float* qkv_b  = (const float*)d_in[5];
  const float* proj_w = (const float*)d_in[6];
  const float* proj_b = (const float*)d_in[7];
  const float* ln2_g  = (const float*)d_in[8];
  const float* ln2_b  = (const float*)d_in[9];
  const float* w1     = (const float*)d_in[10];
  const float* b1     = (const float*)d_in[11];
  const float* w2     = (const float*)d_in[12];
  const float* b2     = (const float*)d_in[13];
  const float* w3     = (const float*)d_in[14];
  const float* b3     = (const float*)d_in[15];
  float* out = (float*)d_out;
  char* ws = (char*)d_ws;

  // workspace layout (bytes) — bf16 weights contiguous for single cvt pass
  unsigned short* hB     = (unsigned short*)(ws + 0);          // [MPAD,768] bf16  16,908,288
  unsigned short* wqkvB  = (unsigned short*)(ws + 16908288);   // [2304,768]        3,538,944
  unsigned short* wprojB = (unsigned short*)(ws + 20447232);   // [768,768]         1,179,648
  unsigned short* w12B   = (unsigned short*)(ws + 21626880);   // [6144,768]        9,437,184
  unsigned short* w3B    = (unsigned short*)(ws + 31064064);   // [768,3072]        4,718,592
  unsigned short* qkvB   = (unsigned short*)(ws + 35782656);   // [MPAD,2304]      50,724,864
  unsigned short* o2B    = (unsigned short*)(ws + 86507520);   // [MPAD,768]       16,908,288
  unsigned short* hidB   = qkvB;  // [MPAD,3072] overlaps dead qkv+o2 after proj

  // all weights -> bf16 in one launch (dest contiguous from wqkvB)
  cvt5_kernel<<<9216, 256, 0, stream>>>(qkv_w, proj_w, w1, w2, w3, wqkvB);

  // attention branch (rope fused into qkv epilogue)
  ln_kernel<<<M_, 256, 0, stream>>>(x, ln1_g, ln1_b, hB);
  gemm_bt<0, 1><<<dim3(18, 86), 256, 0, stream>>>(hB, wqkvB, qkvB, qkv_b, nullptr, freqs, 768, 2304, M_);
  attn_kernel<<<B_ * H_ * QT2_, 256, 0, stream>>>(qkvB, o2B);
  gemm_bt<1, 0><<<dim3(6, 86), 256, 0, stream>>>(o2B, wprojB, out, proj_b, x, nullptr, 768, 768, M_);

  // MLP branch (fused w1|w2 + swiglu -> hid, then w3 + residual)
  ln_kernel<<<M_, 256, 0, stream>>>(out, ln2_g, ln2_b, hB);
  gemm_w12_swiglu<<<dim3(48, 86), 256, 0, stream>>>(hB, w12B, w12B + 3072 * 768, hidB, b1, b2);
  gemm_bt<3, 0><<<dim3(6, 86), 256, 0, stream>>>(hidB, w3B, out, b3, nullptr, nullptr, 3072, 768, M_);
}

// Round 5
// 556.917 us; speedup vs baseline: 1.4477x; 1.0750x over previous
//
#include <hip/hip_runtime.h>
#include <stdint.h>

#define B_ 8
#define N_ 1374
#define C_ 768
#define H_ 12
#define HD_ 64
#define HID_ 3072
#define M_ (B_*N_)        // 10992
#define MPAD_ 11008       // 86 * 128 = 172 * 64
#define QT_ 22            // ceil(N/64)  (j tiles)
#define QT2_ 11           // ceil(N/128) (q tiles)

typedef __attribute__((ext_vector_type(8))) short short8;
typedef __attribute__((ext_vector_type(4))) float f32x4;
typedef __attribute__((ext_vector_type(4))) _Float16 half4;

__device__ __forceinline__ unsigned short f2bf(float f) {
  unsigned u = __float_as_uint(f);
  u += 0x7FFF + ((u >> 16) & 1);
  return (unsigned short)(u >> 16);
}
__device__ __forceinline__ float bf2f(unsigned short h) {
  return __uint_as_float(((unsigned)h) << 16);
}

#if __has_builtin(__builtin_amdgcn_global_load_lds)
#define HAVE_GLL 1
#endif

__device__ __forceinline__ void gld16(const unsigned short* g, unsigned short* l) {
#ifdef HAVE_GLL
  __builtin_amdgcn_global_load_lds((const __attribute__((address_space(1))) void*)g,
                                   (__attribute__((address_space(3))) void*)l, 16, 0, 0);
#else
  *(short8*)l = *(const short8*)g;
#endif
}

// ---------------- single fused f32 -> bf16 conversion for all 5 weights ----------------
__global__ __launch_bounds__(256) void cvt5_kernel(
    const float* __restrict__ s0, const float* __restrict__ s1,
    const float* __restrict__ s2, const float* __restrict__ s3,
    const float* __restrict__ s4, unsigned short* __restrict__ out) {
  int id = blockIdx.x * 256 + threadIdx.x;   // float4 index, grid covers exactly 2359296
  const float* src; int off;
  if (id < 442368)        { src = s0; off = id; }
  else if (id < 589824)   { src = s1; off = id - 442368; }
  else if (id < 1179648)  { src = s2; off = id - 589824; }
  else if (id < 1769472)  { src = s3; off = id - 1179648; }
  else                    { src = s4; off = id - 1769472; }
  float4 v = ((const float4*)src)[off];
  ushort4 o;
  o.x = f2bf(v.x); o.y = f2bf(v.y); o.z = f2bf(v.z); o.w = f2bf(v.w);
  ((ushort4*)out)[id] = o;
}

// ---------------- LayerNorm (f32 in, bf16 out) ----------------
__global__ __launch_bounds__(256) void ln_kernel(const float* __restrict__ in,
    const float* __restrict__ g, const float* __restrict__ bta,
    unsigned short* __restrict__ out) {
  int row = blockIdx.x;
  int t = threadIdx.x;
  const float* xr = in + (size_t)row * C_;
  float v0 = xr[t], v1 = xr[t + 256], v2 = xr[t + 512];
  float s1 = v0 + v1 + v2;
  float s2 = v0*v0 + v1*v1 + v2*v2;
  for (int off = 1; off < 64; off <<= 1) {
    s1 += __shfl_xor(s1, off, 64);
    s2 += __shfl_xor(s2, off, 64);
  }
  __shared__ float r1[4], r2[4];
  int wave = t >> 6, lane = t & 63;
  if (lane == 0) { r1[wave] = s1; r2[wave] = s2; }
  __syncthreads();
  float tot1 = r1[0] + r1[1] + r1[2] + r1[3];
  float tot2 = r2[0] + r2[1] + r2[2] + r2[3];
  float mu = tot1 * (1.0f / C_);
  float var = tot2 * (1.0f / C_) - mu * mu;
  float rs = rsqrtf(var + 1e-5f);
  size_t ob = (size_t)row * C_;
  out[ob + t]       = f2bf((v0 - mu) * rs * g[t]       + bta[t]);
  out[ob + t + 256] = f2bf((v1 - mu) * rs * g[t + 256] + bta[t + 256]);
  out[ob + t + 512] = f2bf((v2 - mu) * rs * g[t + 512] + bta[t + 512]);
}

// ---------------- GEMM: out[M,N] = A[M,K](bf16) * W[N,K]^T(bf16) + epilogue ----------------
// TM: 128 (big-M tiles) or 64 (2x blocks, latency-bound shapes).  BK=64 via two
// stride-32 half-K buffers.  SWZ: supergroup swizzle so the X column-blocks of a
// row-tile share lin%8 (same XCD) -> A row-tile fetched once per L2.
// EPI 0: bf16 out + bias0 (+ fused RoPE on q,k windows)
// EPI 1: f32 out = resid + v + bias, row-guarded
// EPI 3: f32 out += v + bias, row-guarded
template<int EPI, int ROPE, int TM, int SWZ>
__global__ __launch_bounds__(256, (TM == 64) ? 4 : 2) void gemm_bt(
    const unsigned short* __restrict__ A,
    const unsigned short* __restrict__ W,
    void* __restrict__ outp,
    const float* __restrict__ bias0,
    const float* __restrict__ resid,
    const float* __restrict__ freqs,
    int K, int ldo, int Mvalid, int X)
{
  constexpr int MI = TM / 32;   // m-subtiles per wave
  __shared__ __align__(16) unsigned short As[2][TM * 32];
  __shared__ __align__(16) unsigned short Bs[2][4096];
  const int t = threadIdx.x;
  const int lane = t & 63;
  const int wave = t >> 6;
  const int wm = (wave >> 1) * (TM / 2);
  const int wn = (wave & 1) * 64;
  const int lr = lane & 15;
  const int lg = lane >> 4;
  const int lk = lg * 8;
  int bx, by;
  if (SWZ) {
    int Y = gridDim.x / X;
    int lin = blockIdx.x;
    int sgsz = X * 8;
    int sg = lin / sgsz;
    int base_y = sg * 8;
    int rows = Y - base_y; if (rows > 8) rows = 8;
    int within = lin - sg * sgsz;
    by = base_y + within % rows;
    bx = within / rows;
  } else {
    bx = blockIdx.x % X;
    by = blockIdx.x / X;
  }
  const int tm0 = by * TM;
  const int tn0 = bx * 128;
  const int r0 = t >> 2;
  const int c0 = (t & 3) * 8;
  const unsigned short* ga0 = A + (size_t)(tm0 + r0) * K + c0;
  const unsigned short* ga1 = A + (size_t)(tm0 + 64 + r0) * K + c0;   // TM==128 only
  const unsigned short* gb0 = W + (size_t)(tn0 + r0) * K + c0;
  const unsigned short* gb1 = W + (size_t)(tn0 + 64 + r0) * K + c0;
  f32x4 zero = {0.f, 0.f, 0.f, 0.f};
  f32x4 acc[MI][4];
#pragma unroll
  for (int mi = 0; mi < MI; ++mi)
#pragma unroll
    for (int ni = 0; ni < 4; ++ni) acc[mi][ni] = zero;

  for (int kt = 0; kt < K; kt += 64) {
    __syncthreads();
    gld16(ga0 + kt,      &As[0][t * 8]);
    gld16(ga0 + kt + 32, &As[1][t * 8]);
    if (TM == 128) {
      gld16(ga1 + kt,      &As[0][2048 + t * 8]);
      gld16(ga1 + kt + 32, &As[1][2048 + t * 8]);
    }
    gld16(gb0 + kt,      &Bs[0][t * 8]);
    gld16(gb1 + kt,      &Bs[0][2048 + t * 8]);
    gld16(gb0 + kt + 32, &Bs[1][t * 8]);
    gld16(gb1 + kt + 32, &Bs[1][2048 + t * 8]);
    __syncthreads();
#pragma unroll
    for (int u = 0; u < 2; ++u) {
      short8 af[MI], bfr[4];
#pragma unroll
      for (int mi = 0; mi < MI; ++mi) af[mi] = *(const short8*)&As[u][(wm + mi * 16 + lr) * 32 + lk];
#pragma unroll
      for (int ni = 0; ni < 4; ++ni) bfr[ni] = *(const short8*)&Bs[u][(wn + ni * 16 + lr) * 32 + lk];
#pragma unroll
      for (int mi = 0; mi < MI; ++mi)
#pragma unroll
        for (int ni = 0; ni < 4; ++ni)
          acc[mi][ni] = __builtin_amdgcn_mfma_f32_16x16x32_bf16(af[mi], bfr[ni], acc[mi][ni], 0, 0, 0);
    }
  }

  if (EPI == 0) {
    // paired epilogue (cols e and e+32 of a 64-aligned window) for fused RoPE
    bool dorope = ROPE && ((tn0 + wn) < 1536);   // q,k windows only; wave-uniform
#pragma unroll
    for (int mi = 0; mi < MI; ++mi) {
#pragma unroll
      for (int p = 0; p < 2; ++p) {
        int col1 = tn0 + wn + p * 16 + lr;
        int col2 = col1 + 32;
        float bv1 = bias0[col1], bv2 = bias0[col2];
        int e = p * 16 + lr;
#pragma unroll
        for (int r = 0; r < 4; ++r) {
          int row = tm0 + wm + mi * 16 + lg * 4 + r;
          float v1 = acc[mi][p][r] + bv1;
          float v2 = acc[mi][p + 2][r] + bv2;
          float o1 = v1, o2 = v2;
          if (dorope) {
            int n = row % N_;
            float f1 = freqs[n * HD_ + e];
            float f2 = freqs[n * HD_ + e + 32];
            float c1, s1, c2, s2;
            __sincosf(f1, &s1, &c1);
            __sincosf(f2, &s2, &c2);
            o1 = v1 * c1 - v2 * s1;
            o2 = v2 * c2 + v1 * s2;
          }
          size_t base = (size_t)row * ldo;
          ((unsigned short*)outp)[base + col1] = f2bf(o1);
          ((unsigned short*)outp)[base + col2] = f2bf(o2);
        }
      }
    }
  } else {
#pragma unroll
    for (int mi = 0; mi < MI; ++mi) {
#pragma unroll
      for (int ni = 0; ni < 4; ++ni) {
        int col = tn0 + wn + ni * 16 + lr;
        float bval = bias0[col];
#pragma unroll
        for (int r = 0; r < 4; ++r) {
          int row = tm0 + wm + mi * 16 + lg * 4 + r;
          float v = acc[mi][ni][r] + bval;
          size_t idx = (size_t)row * ldo + col;
          if (EPI == 1) {
            if (row < Mvalid) ((float*)outp)[idx] = resid[idx] + v;
          } else {
            if (row < Mvalid) ((float*)outp)[idx] = ((float*)outp)[idx] + v;
          }
        }
      }
    }
  }
}

// ---------------- Fused GEMM: hid = silu(A*W1^T + b1) * (A*W2^T + b2), BK=64 ----------------
__global__ __launch_bounds__(256, 2) void gemm_w12_swiglu(
    const unsigned short* __restrict__ A,     // [MPAD,768]
    const unsigned short* __restrict__ W1,    // [3072,768]
    const unsigned short* __restrict__ W2,    // [3072,768]
    unsigned short* __restrict__ hid,         // [MPAD,3072]
    const float* __restrict__ b1,
    const float* __restrict__ b2)
{
  __shared__ __align__(16) unsigned short As[2][4096];   // 128x32 per half-K
  __shared__ __align__(16) unsigned short B1s[2][2048];  // 64x32 per half-K
  __shared__ __align__(16) unsigned short B2s[2][2048];
  const int t = threadIdx.x;
  const int lane = t & 63;
  const int wave = t >> 6;
  const int wm = (wave >> 1) * 64;
  const int wn = (wave & 1) * 32;
  const int lr = lane & 15;
  const int lg = lane >> 4;
  const int lk = lg * 8;
  const int tm0 = blockIdx.y * 128;
  const int tn0 = blockIdx.x * 64;
  const int r0 = t >> 2;
  const int c0 = (t & 3) * 8;
  const unsigned short* ga0 = A + (size_t)(tm0 + r0) * 768 + c0;
  const unsigned short* ga1 = A + (size_t)(tm0 + 64 + r0) * 768 + c0;
  const unsigned short* g1 = W1 + (size_t)(tn0 + r0) * 768 + c0;
  const unsigned short* g2 = W2 + (size_t)(tn0 + r0) * 768 + c0;
  f32x4 zero = {0.f, 0.f, 0.f, 0.f};
  f32x4 acc1[4][2], acc2[4][2];
#pragma unroll
  for (int mi = 0; mi < 4; ++mi)
#pragma unroll
    for (int ni = 0; ni < 2; ++ni) { acc1[mi][ni] = zero; acc2[mi][ni] = zero; }

  for (int kt = 0; kt < 768; kt += 64) {
    __syncthreads();
    gld16(ga0 + kt,      &As[0][t * 8]);
    gld16(ga1 + kt,      &As[0][2048 + t * 8]);
    gld16(ga0 + kt + 32, &As[1][t * 8]);
    gld16(ga1 + kt + 32, &As[1][2048 + t * 8]);
    gld16(g1 + kt,       &B1s[0][t * 8]);
    gld16(g1 + kt + 32,  &B1s[1][t * 8]);
    gld16(g2 + kt,       &B2s[0][t * 8]);
    gld16(g2 + kt + 32,  &B2s[1][t * 8]);
    __syncthreads();
#pragma unroll
    for (int u = 0; u < 2; ++u) {
      short8 af[4], b1f[2], b2f[2];
#pragma unroll
      for (int mi = 0; mi < 4; ++mi) af[mi] = *(const short8*)&As[u][(wm + mi * 16 + lr) * 32 + lk];
#pragma unroll
      for (int ni = 0; ni < 2; ++ni) {
        b1f[ni] = *(const short8*)&B1s[u][(wn + ni * 16 + lr) * 32 + lk];
        b2f[ni] = *(const short8*)&B2s[u][(wn + ni * 16 + lr) * 32 + lk];
      }
#pragma unroll
      for (int mi = 0; mi < 4; ++mi)
#pragma unroll
        for (int ni = 0; ni < 2; ++ni) {
          acc1[mi][ni] = __builtin_amdgcn_mfma_f32_16x16x32_bf16(af[mi], b1f[ni], acc1[mi][ni], 0, 0, 0);
          acc2[mi][ni] = __builtin_amdgcn_mfma_f32_16x16x32_bf16(af[mi], b2f[ni], acc2[mi][ni], 0, 0, 0);
        }
    }
  }
#pragma unroll
  for (int mi = 0; mi < 4; ++mi) {
#pragma unroll
    for (int ni = 0; ni < 2; ++ni) {
      int col = tn0 + wn + ni * 16 + lr;
      float bv1 = b1[col], bv2 = b2[col];
#pragma unroll
      for (int r = 0; r < 4; ++r) {
        int row = tm0 + wm + mi * 16 + lg * 4 + r;
        float a1 = acc1[mi][ni][r] + bv1;
        float a2 = acc2[mi][ni][r] + bv2;
        float h = a1 / (1.f + __expf(-a1)) * a2;
        hid[(size_t)row * HID_ + col] = f2bf(h);
      }
    }
  }
}

// ---------------- Attention v2: S^T trick, register-resident P ----------------
__global__ __launch_bounds__(256, 2) void attn_kernel(
    const unsigned short* __restrict__ qkv,   // [MPAD_,2304] roped, bf16
    unsigned short* __restrict__ o2)          // [MPAD_,768]  bf16
{
  __shared__ __align__(16) unsigned short Ks[64 * 80];  // K rows, stride 80
  __shared__ __align__(16) _Float16 Vt[64 * 72];        // V^T [d][j], stride 72
  int bidx = blockIdx.x;
  int qt = bidx % QT2_;
  int bh = bidx / QT2_;
  int head = bh % H_;
  int b = bh / H_;
  int t = threadIdx.x, lane = t & 63, wave = t >> 6;
  int lr = lane & 15, lg = lane >> 4;

  short8 bq[2][2];
#pragma unroll
  for (int s = 0; s < 2; ++s) {
    int m = qt * 128 + wave * 32 + s * 16 + lr;
    int mc = (m < N_) ? m : (N_ - 1);
    const unsigned short* qrow = qkv + (size_t)(b * N_ + mc) * 2304 + head * HD_;
    bq[s][0] = *(const short8*)(qrow + lg * 8);
    bq[s][1] = *(const short8*)(qrow + 32 + lg * 8);
  }

  f32x4 zero = {0.f, 0.f, 0.f, 0.f};
  f32x4 acc[2][4];
#pragma unroll
  for (int s = 0; s < 2; ++s)
#pragma unroll
    for (int dt = 0; dt < 4; ++dt) acc[s][dt] = zero;
  float den[2] = {0.f, 0.f};

  const int vp = t & 31;        // j-pair 0..31
  const int vc = t >> 5;        // d-chunk 0..7

  for (int jt = 0; jt < QT_; ++jt) {
    __syncthreads();
#pragma unroll
    for (int u = t; u < 512; u += 256) {
      int row = u >> 3, c = u & 7;
      int j = jt * 64 + row;
      int jc = (j < N_) ? j : (N_ - 1);
      const unsigned short* src = qkv + (size_t)(b * N_ + jc) * 2304 + 768 + head * HD_ + c * 8;
      *(short8*)&Ks[row * 80 + c * 8] = *(const short8*)src;
    }
    {
      int j0 = jt * 64 + 2 * vp;
      int j1 = j0 + 1;
      int j0c = (j0 < N_) ? j0 : (N_ - 1);
      int j1c = (j1 < N_) ? j1 : (N_ - 1);
      const unsigned short* s0 = qkv + (size_t)(b * N_ + j0c) * 2304 + 1536 + head * HD_ + vc * 8;
      const unsigned short* s1 = qkv + (size_t)(b * N_ + j1c) * 2304 + 1536 + head * HD_ + vc * 8;
      short8 v0 = *(const short8*)s0;
      short8 v1 = *(const short8*)s1;
#pragma unroll
      for (int i = 0; i < 8; ++i) {
        _Float16 lo = (_Float16)bf2f((unsigned short)v0[i]);
        _Float16 hi = (_Float16)bf2f((unsigned short)v1[i]);
        unsigned w = (unsigned)__builtin_bit_cast(unsigned short, lo)
                   | ((unsigned)__builtin_bit_cast(unsigned short, hi) << 16);
        *(unsigned*)&Vt[(vc * 8 + i) * 72 + 2 * vp] = w;
      }
    }
    __syncthreads();
#pragma unroll
    for (int st = 0; st < 4; ++st) {
      short8 ak0 = *(const short8*)&Ks[(st * 16 + lr) * 80 + lg * 8];
      short8 ak1 = *(const short8*)&Ks[(st * 16 + lr) * 80 + 32 + lg * 8];
      int jb = jt * 64 + st * 16 + lg * 4;
      half4 pf[2];
#pragma unroll
      for (int s = 0; s < 2; ++s) {
        f32x4 sc = zero;
        sc = __builtin_amdgcn_mfma_f32_16x16x32_bf16(ak0, bq[s][0], sc, 0, 0, 0);
        sc = __builtin_amdgcn_mfma_f32_16x16x32_bf16(ak1, bq[s][1], sc, 0, 0, 0);
        float dsum = 0.f;
#pragma unroll
        for (int r = 0; r < 4; ++r) {
          float pv = (jb + r < N_) ? __expf(sc[r] * 0.125f) : 0.f;
          dsum += pv;
          pf[s][r] = (_Float16)pv;
        }
        den[s] += dsum;
      }
#pragma unroll
      for (int dt = 0; dt < 4; ++dt) {
        half4 bv = *(const half4*)&Vt[(dt * 16 + lr) * 72 + st * 16 + lg * 4];
        acc[0][dt] = __builtin_amdgcn_mfma_f32_16x16x16f16(pf[0], bv, acc[0][dt], 0, 0, 0);
        acc[1][dt] = __builtin_amdgcn_mfma_f32_16x16x16f16(pf[1], bv, acc[1][dt], 0, 0, 0);
      }
    }
  }
#pragma unroll
  for (int s = 0; s < 2; ++s) {
    den[s] += __shfl_xor(den[s], 16, 64);
    den[s] += __shfl_xor(den[s], 32, 64);
  }
#pragma unroll
  for (int s = 0; s < 2; ++s) {
#pragma unroll
    for (int r = 0; r < 4; ++r) {
      float dm = __shfl(den[s], lg * 4 + r, 64);
      int m = qt * 128 + wave * 32 + s * 16 + lg * 4 + r;
      if (m < N_) {
        float invd = 1.f / dm;
        unsigned short* orow = o2 + (size_t)(b * N_ + m) * C_ + head * HD_;
#pragma unroll
        for (int dt = 0; dt < 4; ++dt)
          orow[dt * 16 + lr] = f2bf(acc[s][dt][r] * invd);
      }
    }
  }
}

extern "C" void kernel_launch(void* const* d_in, const int* in_sizes, int n_in,
                              void* d_out, int out_size, void* d_ws, size_t ws_size,
                              hipStream_t stream) {
  const float* x      = (const float*)d_in[0];
  const float* freqs  = (const float*)d_in[1];
  const float* ln1_g  = (const float*)d_in[2];
  const float* ln1_b  = (const float*)d_in[3];
  const float* qkv_w  = (const float*)d_in[4];
  const float* qkv_b  = (const float*)d_in[5];
  const float* proj_w = (const float*)d_in[6];
  const float* proj_b = (const float*)d_in[7];
  const float* ln2_g  = (const float*)d_in[8];
  const float* ln2_b  = (const float*)d_in[9];
  const float* w1     = (const float*)d_in[10];
  const float* b1     = (const float*)d_in[11];
  const float* w2     = (const float*)d_in[12];
  const float* b2     = (const float*)d_in[13];
  const float* w3     = (const float*)d_in[14];
  const float* b3     = (const float*)d_in[15];
  float* out = (float*)d_out;
  char* ws = (char*)d_ws;

  // workspace layout (bytes) — bf16 weights contiguous for single cvt pass
  unsigned short* hB     = (unsigned short*)(ws + 0);          // [MPAD,768] bf16  16,908,288
  unsigned short* wqkvB  = (unsigned short*)(ws + 16908288);   // [2304,768]        3,538,944
  unsigned short* wprojB = (unsigned short*)(ws + 20447232);   // [768,768]         1,179,648
  unsigned short* w12B   = (unsigned short*)(ws + 21626880);   // [6144,768]        9,437,184
  unsigned short* w3B    = (unsigned short*)(ws + 31064064);   // [768,3072]        4,718,592
  unsigned short* qkvB   = (unsigned short*)(ws + 35782656);   // [MPAD,2304]      50,724,864
  unsigned short* o2B    = (unsigned short*)(ws + 86507520);   // [MPAD,768]       16,908,288
  unsigned short* hidB   = qkvB;  // [MPAD,3072] overlaps dead qkv+o2 after proj

  // all weights -> bf16 in one launch (dest contiguous from wqkvB)
  cvt5_kernel<<<9216, 256, 0, stream>>>(qkv_w, proj_w, w1, w2, w3, wqkvB);

  // attention branch (rope fused into qkv epilogue)
  ln_kernel<<<M_, 256, 0, stream>>>(x, ln1_g, ln1_b, hB);
  gemm_bt<0, 1, 128, 1><<<18 * 86, 256, 0, stream>>>(hB, wqkvB, qkvB, qkv_b, nullptr, freqs, 768, 2304, M_, 18);
  attn_kernel<<<B_ * H_ * QT2_, 256, 0, stream>>>(qkvB, o2B);
  gemm_bt<1, 0, 64, 1><<<6 * 172, 256, 0, stream>>>(o2B, wprojB, out, proj_b, x, nullptr, 768, 768, M_, 6);

  // MLP branch (fused w1|w2 + swiglu -> hid, then w3 + residual)
  ln_kernel<<<M_, 256, 0, stream>>>(out, ln2_g, ln2_b, hB);
  gemm_w12_swiglu<<<dim3(48, 86), 256, 0, stream>>>(hB, w12B, w12B + 3072 * 768, hidB, b1, b2);
  gemm_bt<3, 0, 64, 1><<<6 * 172, 256, 0, stream>>>(hidB, w3B, out, b3, nullptr, nullptr, 3072, 768, M_, 6);
}